// Round 6
// baseline (402.898 us; speedup 1.0000x reference)
//
#include <hip/hip_runtime.h>
#include <math.h>

#define B_ 4
#define T_ 2048
#define C_ 1024
#define H_ 16
#define NROWS (B_*T_)   // 8192

typedef short s8v  __attribute__((ext_vector_type(8)));
typedef float f4v  __attribute__((ext_vector_type(4)));
typedef unsigned short u16v4 __attribute__((ext_vector_type(4)));

static __device__ __forceinline__ unsigned short f2bf(float x) {
    unsigned u = __float_as_uint(x);
    unsigned r = u + 0x7fffu + ((u >> 16) & 1u);
    return (unsigned short)(r >> 16);
}

static __device__ __forceinline__ void gload_lds16(const void* g, void* l) {
    __builtin_amdgcn_global_load_lds(
        (const __attribute__((address_space(1))) void*)g,
        (__attribute__((address_space(3))) void*)l, 16, 0, 0);
}

// ---------------- LayerNorm -> bf16 out (one block per row of 1024) ----------------
__global__ __launch_bounds__(256) void ln_bf16(const float* __restrict__ x,
        const float* __restrict__ w, const float* __restrict__ b,
        unsigned short* __restrict__ out, const int* __restrict__ flag)
{
    if (flag && flag[0] == 0) return;
    int row = blockIdx.x;
    int tid = threadIdx.x;
    const float4* xr = (const float4*)(x + (size_t)row * C_);
    float4 v = xr[tid];
    float s  = v.x + v.y + v.z + v.w;
    float ss = v.x*v.x + v.y*v.y + v.z*v.z + v.w*v.w;
    #pragma unroll
    for (int off = 32; off > 0; off >>= 1) {
        s  += __shfl_down(s,  off, 64);
        ss += __shfl_down(ss, off, 64);
    }
    __shared__ float rs[4], rss[4];
    __shared__ float smu, srstd;
    int wave = tid >> 6, lane = tid & 63;
    if (lane == 0) { rs[wave] = s; rss[wave] = ss; }
    __syncthreads();
    if (tid == 0) {
        float S  = rs[0]+rs[1]+rs[2]+rs[3];
        float SS = rss[0]+rss[1]+rss[2]+rss[3];
        float mu = S * (1.0f/C_);
        float var = SS * (1.0f/C_) - mu*mu;
        smu = mu; srstd = rsqrtf(var + 1e-5f);
    }
    __syncthreads();
    float mu = smu, rstd = srstd;
    float4 wv = ((const float4*)w)[tid];
    float4 bv = ((const float4*)b)[tid];
    u16v4 o;
    o.x = f2bf((v.x-mu)*rstd*wv.x + bv.x);
    o.y = f2bf((v.y-mu)*rstd*wv.y + bv.y);
    o.z = f2bf((v.z-mu)*rstd*wv.z + bv.z);
    o.w = f2bf((v.w-mu)*rstd*wv.w + bv.w);
    *(u16v4*)(out + (size_t)row * C_ + tid*4) = o;
}

// ---------------- fp32 -> bf16 convert ----------------
__global__ __launch_bounds__(256) void cvt_bf16(const float* __restrict__ in,
        unsigned short* __restrict__ out, int n4, const int* __restrict__ flag)
{
    if (flag && flag[0] == 0) return;
    int i = blockIdx.x * 256 + threadIdx.x;
    if (i < n4) {
        float4 v = ((const float4*)in)[i];
        u16v4 o = { f2bf(v.x), f2bf(v.y), f2bf(v.z), f2bf(v.w) };
        *(u16v4*)(out + (size_t)i*4) = o;
    }
}

// merged flagged conversion of cproj/fc/fcproj weights (9*C*C elements total)
__global__ __launch_bounds__(256) void cvt3_bf16(
        const float* __restrict__ cprojw, const float* __restrict__ fcw,
        const float* __restrict__ fcpw,
        unsigned short* __restrict__ wproj, unsigned short* __restrict__ wfc,
        unsigned short* __restrict__ wfcp, const int* __restrict__ flag)
{
    if (flag[0] == 0) return;
    int i = blockIdx.x * 256 + threadIdx.x;   // vec4 index, < 9*C*C/4
    const int n1 = C_*C_/4;          // cproj
    const int n2 = n1 + C_*C_;       // + fc (4C*C elems = C*C vec4)
    const float* src; unsigned short* dst; int j;
    if (i < n1)      { src = cprojw; dst = wproj; j = i; }
    else if (i < n2) { src = fcw;    dst = wfc;   j = i - n1; }
    else             { src = fcpw;   dst = wfcp;  j = i - n2; }
    float4 v = ((const float4*)src)[j];
    u16v4 o = { f2bf(v.x), f2bf(v.y), f2bf(v.z), f2bf(v.w) };
    *(u16v4*)(dst + (size_t)j*4) = o;
}

__global__ void zero_kernel(float* p, int n) {
    int i = blockIdx.x * 256 + threadIdx.x;
    if (i < n) p[i] = 0.f;
}

// ---------------- bf16 MFMA GEMM: C[m,n] = sum_k A[m][k]*Bw[n][k] ----------------
// EPI: 1 = bias + exact GELU -> bf16 ; 2 = bias(opt) + fp32 residual -> fp32
//      3 = bias -> bf16 head-major qkv scatter ; 4 = bias + (res + v)*cm -> fp32
template<int EPI>
__global__ __launch_bounds__(256) void gemm_bf16(
    const unsigned short* __restrict__ A,
    const unsigned short* __restrict__ Bw,
    const float* __restrict__ bias,
    const float* __restrict__ res,
    float* __restrict__ Cout, unsigned short* __restrict__ Cbf,
    int K, int lda, int ldb, int ldc, int ncoff,
    const float* __restrict__ cmv,
    unsigned short* __restrict__ qh, unsigned short* __restrict__ kh,
    unsigned short* __restrict__ vh, const int* __restrict__ flag)
{
    if (flag && flag[0] == 0) return;
    __shared__ unsigned short As[128*64];
    __shared__ unsigned short Bs[128*64];
    int tid = threadIdx.x;
    int w = tid >> 6, lane = tid & 63, quad = lane >> 4, l16 = lane & 15;
    int wr = w >> 1, wc = w & 1;
    int m0 = blockIdx.y * 128, n0 = blockIdx.x * 128;

    size_t offA[4], offB[4];
    #pragma unroll
    for (int j = 0; j < 4; j++) {
        int ci = j*256 + tid;
        int mr = ci >> 3, kcs = ci & 7;
        int kc = kcs ^ (mr & 7);
        offA[j] = (size_t)(m0 + mr) * lda + kc*8;
        offB[j] = (size_t)(n0 + mr) * ldb + kc*8;
    }

    f4v acc[4][4];
    #pragma unroll
    for (int i = 0; i < 4; i++)
        #pragma unroll
        for (int j = 0; j < 4; j++) { acc[i][j][0]=0.f; acc[i][j][1]=0.f; acc[i][j][2]=0.f; acc[i][j][3]=0.f; }

    for (int k0 = 0; k0 < K; k0 += 64) {
        __syncthreads();
        #pragma unroll
        for (int j = 0; j < 4; j++) {
            gload_lds16(A  + offA[j] + k0, &As[(j*256 + (w<<6))*8]);
            gload_lds16(Bw + offB[j] + k0, &Bs[(j*256 + (w<<6))*8]);
        }
        __syncthreads();
        #pragma unroll
        for (int c = 0; c < 2; c++) {
            s8v af[4], bf[4];
            int sw = ((c<<2) + quad) ^ (l16 & 7);
            #pragma unroll
            for (int i = 0; i < 4; i++) {
                int mr = wr*64 + i*16 + l16;
                af[i] = *(const s8v*)&As[mr*64 + sw*8];
                int nr = wc*64 + i*16 + l16;
                bf[i] = *(const s8v*)&Bs[nr*64 + sw*8];
            }
            #pragma unroll
            for (int i = 0; i < 4; i++)
                #pragma unroll
                for (int j = 0; j < 4; j++)
                    acc[i][j] = __builtin_amdgcn_mfma_f32_16x16x32_bf16(af[i], bf[j], acc[i][j], 0, 0, 0);
        }
    }

    #pragma unroll
    for (int j = 0; j < 4; j++) {
        int ncol = n0 + wc*64 + j*16 + l16;
        float bv = bias ? bias[ncol] : 0.f;
        int hh = 0, dd = 0;
        unsigned short* basep = nullptr;
        if (EPI == 3) {
            int ncolg = ncol + ncoff;
            int sec = ncolg >> 10;
            int hn = ncolg & 1023;
            hh = hn >> 6; dd = hn & 63;
            basep = (sec == 0) ? qh : (sec == 1) ? kh : vh;
        }
        #pragma unroll
        for (int i = 0; i < 4; i++) {
            #pragma unroll
            for (int reg = 0; reg < 4; reg++) {
                int m = m0 + wr*64 + i*16 + quad*4 + reg;
                float v = acc[i][j][reg] + bv;
                if (EPI == 1) {
                    v = 0.5f * v * (1.0f + erff(v * 0.70710678118654752f));
                    Cbf[(size_t)m*ldc + ncol] = f2bf(v);
                } else if (EPI == 2) {
                    Cout[(size_t)m*ldc + ncol] = v + res[(size_t)m*ldc + ncol];
                } else if (EPI == 3) {
                    int bb = m >> 11, t = m & 2047;
                    basep[(((size_t)(bb*H_ + hh))*T_ + t)*64 + dd] = f2bf(v);
                } else if (EPI == 4) {
                    Cout[(size_t)m*ldc + ncol] = (res[(size_t)m*ldc + ncol] + v) * cmv[m];
                }
            }
        }
    }
}

// ---- QK^T score tile: accS[nt] covers S[q0w+quad*4+reg][k0+nt*16+l16] ----
static __device__ __forceinline__ void qk_tile(const unsigned short* __restrict__ ks,
        s8v a0, s8v a1, int quad, int l16, f4v accS[4])
{
    #pragma unroll
    for (int nt = 0; nt < 4; nt++) { accS[nt][0]=0.f; accS[nt][1]=0.f; accS[nt][2]=0.f; accS[nt][3]=0.f; }
    #pragma unroll
    for (int c = 0; c < 2; c++) {
        #pragma unroll
        for (int nt = 0; nt < 4; nt++) {
            s8v bk = *(const s8v*)&ks[((nt*16 + l16)*8 + (((c<<2)+quad) ^ (l16 & 7)))*8];
            accS[nt] = __builtin_amdgcn_mfma_f32_16x16x32_bf16(c ? a1 : a0, bk, accS[nt], 0, 0, 0);
        }
    }
}

// ---------------- importance-only attention ----------------
// Block = (bh, pair p): q-tiles p and 31-p (64 rows each), uniform 33 tile-computes
// per pass. Union K-tiles loaded once, double-buffered global_load_lds prefetch.
__global__ __launch_bounds__(256) void attn_imp(
    const unsigned short* __restrict__ qh, const unsigned short* __restrict__ kh,
    const float* __restrict__ amask, float* __restrict__ imp)
{
    __shared__ unsigned short Ks[2][64*64];
    __shared__ float colws[64];

    int tid = threadIdx.x;
    int w = tid >> 6, lane = tid & 63, quad = lane >> 4, l16 = lane & 15;
    int bh = blockIdx.x & 63;
    int p  = blockIdx.x >> 6;          // 0..15
    int b  = bh >> 4;
    int qtB = 31 - p;
    int ntiles = 32 - p;               // union of k-tiles needed

    const unsigned short* qp = qh + (size_t)bh*T_*64;
    const unsigned short* kp = kh + (size_t)bh*T_*64;
    const float* amp = amask + b*T_;

    int qA0 = p*64 + 16*w, qB0 = qtB*64 + 16*w;
    s8v aQA0 = *(const s8v*)(qp + (size_t)(qA0 + l16)*64 + quad*8);
    s8v aQA1 = *(const s8v*)(qp + (size_t)(qA0 + l16)*64 + 32 + quad*8);
    s8v aQB0 = *(const s8v*)(qp + (size_t)(qB0 + l16)*64 + quad*8);
    s8v aQB1 = *(const s8v*)(qp + (size_t)(qB0 + l16)*64 + 32 + quad*8);

    int r0 = tid >> 3,       c0 = (tid & 7) ^ (r0 & 7);
    int r1 = (256+tid) >> 3, c1 = ((256+tid) & 7) ^ (r1 & 7);

    // ---- pass 1: row sums of exp(s) ----
    float lrowA[4] = {0.f,0.f,0.f,0.f}, lrowB[4] = {0.f,0.f,0.f,0.f};
    {
        int k0 = 0;
        gload_lds16(kp + ((size_t)(k0+r0)*64 + c0*8), &Ks[0][(w*64)*8]);
        gload_lds16(kp + ((size_t)(k0+r1)*64 + c1*8), &Ks[0][(256 + w*64)*8]);
    }
    for (int it = 0; it < ntiles; ++it) {
        int k0 = it * 64;
        __syncthreads();
        if (it + 1 < ntiles) {
            int kn = k0 + 64, bufn = (it+1) & 1;
            gload_lds16(kp + ((size_t)(kn+r0)*64 + c0*8), &Ks[bufn][(w*64)*8]);
            gload_lds16(kp + ((size_t)(kn+r1)*64 + c1*8), &Ks[bufn][(256 + w*64)*8]);
        }
        const unsigned short* ks = Ks[it & 1];
        float mk[4];
        #pragma unroll
        for (int nt = 0; nt < 4; nt++) mk[nt] = amp[k0 + nt*16 + l16];
        bool allm = __all(mk[0] != 0.f && mk[1] != 0.f && mk[2] != 0.f && mk[3] != 0.f);

        { // q-tile B: needed every tile
            f4v accS[4];
            qk_tile(ks, aQB0, aQB1, quad, l16, accS);
            if ((k0 + 63 <= qB0) && allm) {
                #pragma unroll
                for (int nt = 0; nt < 4; nt++)
                    #pragma unroll
                    for (int reg = 0; reg < 4; reg++)
                        lrowB[reg] += __expf(accS[nt][reg] * 0.125f);
            } else {
                #pragma unroll
                for (int nt = 0; nt < 4; nt++) {
                    int kg = k0 + nt*16 + l16;
                    #pragma unroll
                    for (int reg = 0; reg < 4; reg++) {
                        bool val = (kg <= qB0 + quad*4 + reg) && (mk[nt] != 0.f);
                        float e = __expf(accS[nt][reg] * 0.125f);
                        lrowB[reg] += val ? e : 0.f;
                    }
                }
            }
        }
        if (k0 <= qA0 + 15) { // q-tile A: tiles 0..p
            f4v accS[4];
            qk_tile(ks, aQA0, aQA1, quad, l16, accS);
            if ((k0 + 63 <= qA0) && allm) {
                #pragma unroll
                for (int nt = 0; nt < 4; nt++)
                    #pragma unroll
                    for (int reg = 0; reg < 4; reg++)
                        lrowA[reg] += __expf(accS[nt][reg] * 0.125f);
            } else {
                #pragma unroll
                for (int nt = 0; nt < 4; nt++) {
                    int kg = k0 + nt*16 + l16;
                    #pragma unroll
                    for (int reg = 0; reg < 4; reg++) {
                        bool val = (kg <= qA0 + quad*4 + reg) && (mk[nt] != 0.f);
                        float e = __expf(accS[nt][reg] * 0.125f);
                        lrowA[reg] += val ? e : 0.f;
                    }
                }
            }
        }
    }
    float linvA[4], linvB[4];
    #pragma unroll
    for (int reg = 0; reg < 4; reg++) {
        float v = lrowA[reg];
        v += __shfl_xor(v, 1); v += __shfl_xor(v, 2);
        v += __shfl_xor(v, 4); v += __shfl_xor(v, 8);
        linvA[reg] = (v > 0.f) ? 1.0f / v : 0.f;
        float u = lrowB[reg];
        u += __shfl_xor(u, 1); u += __shfl_xor(u, 2);
        u += __shfl_xor(u, 4); u += __shfl_xor(u, 8);
        linvB[reg] = (u > 0.f) ? 1.0f / u : 0.f;
    }

    // ---- pass 2: colsums of p = exp(s)/l ----
    if (tid < 64) colws[tid] = 0.f;
    __syncthreads();
    {
        int k0 = 0;
        gload_lds16(kp + ((size_t)(k0+r0)*64 + c0*8), &Ks[0][(w*64)*8]);
        gload_lds16(kp + ((size_t)(k0+r1)*64 + c1*8), &Ks[0][(256 + w*64)*8]);
    }
    for (int it = 0; it < ntiles; ++it) {
        int k0 = it * 64;
        __syncthreads();
        if (it + 1 < ntiles) {
            int kn = k0 + 64, bufn = (it+1) & 1;
            gload_lds16(kp + ((size_t)(kn+r0)*64 + c0*8), &Ks[bufn][(w*64)*8]);
            gload_lds16(kp + ((size_t)(kn+r1)*64 + c1*8), &Ks[bufn][(256 + w*64)*8]);
        }
        if (tid < 64 && it > 0) {
            atomicAdd(&imp[b*T_ + (k0 - 64) + tid], colws[tid]);
            colws[tid] = 0.f;
        }
        const unsigned short* ks = Ks[it & 1];
        float mk[4];
        #pragma unroll
        for (int nt = 0; nt < 4; nt++) mk[nt] = amp[k0 + nt*16 + l16];
        bool allm = __all(mk[0] != 0.f && mk[1] != 0.f && mk[2] != 0.f && mk[3] != 0.f);

        float cs[4] = {0.f, 0.f, 0.f, 0.f};
        { // B
            f4v accS[4];
            qk_tile(ks, aQB0, aQB1, quad, l16, accS);
            if ((k0 + 63 <= qB0) && allm) {
                #pragma unroll
                for (int nt = 0; nt < 4; nt++)
                    #pragma unroll
                    for (int reg = 0; reg < 4; reg++)
                        cs[nt] += __expf(accS[nt][reg] * 0.125f) * linvB[reg];
            } else {
                #pragma unroll
                for (int nt = 0; nt < 4; nt++) {
                    int kg = k0 + nt*16 + l16;
                    #pragma unroll
                    for (int reg = 0; reg < 4; reg++) {
                        bool val = (kg <= qB0 + quad*4 + reg) && (mk[nt] != 0.f);
                        float e = __expf(accS[nt][reg] * 0.125f) * linvB[reg];
                        cs[nt] += val ? e : 0.f;
                    }
                }
            }
        }
        if (k0 <= qA0 + 15) { // A
            f4v accS[4];
            qk_tile(ks, aQA0, aQA1, quad, l16, accS);
            if ((k0 + 63 <= qA0) && allm) {
                #pragma unroll
                for (int nt = 0; nt < 4; nt++)
                    #pragma unroll
                    for (int reg = 0; reg < 4; reg++)
                        cs[nt] += __expf(accS[nt][reg] * 0.125f) * linvA[reg];
            } else {
                #pragma unroll
                for (int nt = 0; nt < 4; nt++) {
                    int kg = k0 + nt*16 + l16;
                    #pragma unroll
                    for (int reg = 0; reg < 4; reg++) {
                        bool val = (kg <= qA0 + quad*4 + reg) && (mk[nt] != 0.f);
                        float e = __expf(accS[nt][reg] * 0.125f) * linvA[reg];
                        cs[nt] += val ? e : 0.f;
                    }
                }
            }
        }
        #pragma unroll
        for (int nt = 0; nt < 4; nt++) {
            float v = cs[nt];
            v += __shfl_xor(v, 16);
            v += __shfl_xor(v, 32);
            if (quad == 0) atomicAdd(&colws[nt*16 + l16], v);
        }
    }
    __syncthreads();
    if (tid < 64) atomicAdd(&imp[b*T_ + (ntiles-1)*64 + tid], colws[tid]);
}

// ---------------- mask finalize: cm, loss, survivor count ----------------
__global__ __launch_bounds__(256) void mask_finalize(
    const float* __restrict__ imp, const float* __restrict__ amask,
    const float* __restrict__ prot, const float* __restrict__ thr,
    float* __restrict__ mask_out, float* __restrict__ loss_out,
    int* __restrict__ nsurv)
{
    int i = blockIdx.x * 256 + threadIdx.x;
    float impv = imp[i] * (1.0f / (float)(H_ * T_));
    float pm = (impv >= thr[0]) ? 1.f : 0.f;
    if (prot[i] > 0.f) pm = 1.f;
    float cm = amask[i] * pm;
    mask_out[i] = cm;
    if (i == 0) loss_out[0] = 0.f;
    unsigned long long bal = __ballot(cm != 0.f);
    int cnt = __popcll(bal);
    __shared__ int bs;
    if (threadIdx.x == 0) bs = 0;
    __syncthreads();
    if ((threadIdx.x & 63) == 0 && cnt) atomicAdd(&bs, cnt);
    __syncthreads();
    if (threadIdx.x == 0 && bs) atomicAdd(nsurv, bs);
}

// ---------------- full attention (dense fallback; R3-proven) ----------------
__global__ __launch_bounds__(256) void attn_full(
    const unsigned short* __restrict__ qh, const unsigned short* __restrict__ kh,
    const unsigned short* __restrict__ vh, const float* __restrict__ amask,
    unsigned short* __restrict__ y, const int* __restrict__ flag)
{
    if (flag[0] == 0) return;
    __shared__ unsigned short Ks[64][72];
    __shared__ unsigned short Vt[64][72];
    __shared__ unsigned short Ps[4][16][72];
    __shared__ float mks[64];

    int tid = threadIdx.x;
    int w = tid >> 6, lane = tid & 63, quad = lane >> 4, l16 = lane & 15;
    int nqt = T_ / 64;
    int qt = blockIdx.x % nqt;
    int bh = blockIdx.x / nqt;
    int b = bh >> 4, h = bh & 15;
    int q0 = qt * 64;

    const unsigned short* qp = qh + (size_t)bh * T_ * 64;
    const unsigned short* kp = kh + (size_t)bh * T_ * 64;
    const unsigned short* vp = vh + (size_t)bh * T_ * 64;

    int qrow = q0 + 16*w + l16;
    s8v aQ0 = *(const s8v*)(qp + (size_t)qrow*64 + quad*8);
    s8v aQ1 = *(const s8v*)(qp + (size_t)qrow*64 + 32 + quad*8);

    int qwmax = q0 + 16*w + 15;
    int ntiles = qt + 1;
    int qg = q0 + 16*w + quad*4;

    float lrow[4] = {0.f, 0.f, 0.f, 0.f};
    for (int it = 0; it < ntiles; ++it) {
        int k0 = it * 64;
        __syncthreads();
        for (int cid = tid; cid < 512; cid += 256) {
            int row = cid >> 3, ch = cid & 7;
            *(s8v*)&Ks[row][ch*8] = *(const s8v*)(kp + (size_t)(k0+row)*64 + ch*8);
        }
        if (tid < 64) mks[tid] = amask[b*T_ + k0 + tid];
        __syncthreads();
        if (k0 > qwmax) continue;
        f4v accS[4];
        #pragma unroll
        for (int nt = 0; nt < 4; nt++) { accS[nt][0]=0.f; accS[nt][1]=0.f; accS[nt][2]=0.f; accS[nt][3]=0.f; }
        #pragma unroll
        for (int nt = 0; nt < 4; nt++) {
            s8v b0 = *(const s8v*)&Ks[nt*16 + l16][quad*8];
            s8v b1 = *(const s8v*)&Ks[nt*16 + l16][32 + quad*8];
            accS[nt] = __builtin_amdgcn_mfma_f32_16x16x32_bf16(aQ0, b0, accS[nt], 0, 0, 0);
            accS[nt] = __builtin_amdgcn_mfma_f32_16x16x32_bf16(aQ1, b1, accS[nt], 0, 0, 0);
        }
        #pragma unroll
        for (int nt = 0; nt < 4; nt++) {
            int kg = k0 + nt*16 + l16;
            float mkv = mks[nt*16 + l16];
            #pragma unroll
            for (int reg = 0; reg < 4; reg++) {
                bool val = (kg <= qg + reg) && (mkv != 0.f);
                float e = __expf(accS[nt][reg] * 0.125f);
                lrow[reg] += val ? e : 0.f;
            }
        }
    }
    float linv[4];
    #pragma unroll
    for (int reg = 0; reg < 4; reg++) {
        float v = lrow[reg];
        v += __shfl_xor(v, 1); v += __shfl_xor(v, 2);
        v += __shfl_xor(v, 4); v += __shfl_xor(v, 8);
        linv[reg] = (v > 0.f) ? 1.0f / v : 0.f;
    }

    f4v accO[4];
    #pragma unroll
    for (int nt = 0; nt < 4; nt++) { accO[nt][0]=0.f; accO[nt][1]=0.f; accO[nt][2]=0.f; accO[nt][3]=0.f; }

    for (int it = 0; it < ntiles; ++it) {
        int k0 = it * 64;
        __syncthreads();
        for (int cid = tid; cid < 512; cid += 256) {
            int row = cid >> 3, ch = cid & 7;
            s8v kv = *(const s8v*)(kp + (size_t)(k0+row)*64 + ch*8);
            *(s8v*)&Ks[row][ch*8] = kv;
            s8v vv = *(const s8v*)(vp + (size_t)(k0+row)*64 + ch*8);
            #pragma unroll
            for (int j = 0; j < 8; j++) Vt[ch*8 + j][row] = (unsigned short)vv[j];
        }
        if (tid < 64) mks[tid] = amask[b*T_ + k0 + tid];
        __syncthreads();
        if (k0 > qwmax) continue;
        f4v accS[4];
        #pragma unroll
        for (int nt = 0; nt < 4; nt++) { accS[nt][0]=0.f; accS[nt][1]=0.f; accS[nt][2]=0.f; accS[nt][3]=0.f; }
        #pragma unroll
        for (int nt = 0; nt < 4; nt++) {
            s8v b0 = *(const s8v*)&Ks[nt*16 + l16][quad*8];
            s8v b1 = *(const s8v*)&Ks[nt*16 + l16][32 + quad*8];
            accS[nt] = __builtin_amdgcn_mfma_f32_16x16x32_bf16(aQ0, b0, accS[nt], 0, 0, 0);
            accS[nt] = __builtin_amdgcn_mfma_f32_16x16x32_bf16(aQ1, b1, accS[nt], 0, 0, 0);
        }
        #pragma unroll
        for (int nt = 0; nt < 4; nt++) {
            int kg = k0 + nt*16 + l16;
            float mkv = mks[nt*16 + l16];
            #pragma unroll
            for (int reg = 0; reg < 4; reg++) {
                bool val = (kg <= qg + reg) && (mkv != 0.f);
                float p = val ? __expf(accS[nt][reg] * 0.125f) * linv[reg] : 0.f;
                Ps[w][quad*4 + reg][nt*16 + l16] = f2bf(p);
            }
        }
        s8v aP0 = *(const s8v*)&Ps[w][l16][quad*8];
        s8v aP1 = *(const s8v*)&Ps[w][l16][32 + quad*8];
        #pragma unroll
        for (int nt = 0; nt < 4; nt++) {
            s8v bv0 = *(const s8v*)&Vt[nt*16 + l16][quad*8];
            s8v bv1 = *(const s8v*)&Vt[nt*16 + l16][32 + quad*8];
            accO[nt] = __builtin_amdgcn_mfma_f32_16x16x32_bf16(aP0, bv0, accO[nt], 0, 0, 0);
            accO[nt] = __builtin_amdgcn_mfma_f32_16x16x32_bf16(aP1, bv1, accO[nt], 0, 0, 0);
        }
    }
    #pragma unroll
    for (int nt = 0; nt < 4; nt++) {
        #pragma unroll
        for (int reg = 0; reg < 4; reg++) {
            int q = q0 + 16*w + quad*4 + reg;
            y[((size_t)(b*T_ + q))*C_ + h*64 + nt*16 + l16] = f2bf(accO[nt][reg]);
        }
    }
}

// ---------------- all-pruned fast path: one-row MLP + broadcast ----------------
__global__ __launch_bounds__(256) void ap_fc(const int* __restrict__ nsurv,
        const float* __restrict__ ln2b, const float* __restrict__ fcw,
        const float* __restrict__ fcb, float* __restrict__ abuf)
{
    if (nsurv[0] != 0) return;
    int j = blockIdx.x * 4 + (threadIdx.x >> 6);
    int lane = threadIdx.x & 63;
    const float* wr = fcw + (size_t)j * C_;
    float s = 0.f;
    for (int k = lane; k < C_; k += 64) s += ln2b[k] * wr[k];
    #pragma unroll
    for (int off = 32; off > 0; off >>= 1) s += __shfl_down(s, off, 64);
    if (lane == 0) {
        float v = fcb[j] + s;
        abuf[j] = 0.5f * v * (1.0f + erff(v * 0.70710678118654752f));
    }
}

__global__ __launch_bounds__(256) void ap_fcp(const int* __restrict__ nsurv,
        const float* __restrict__ abuf, const float* __restrict__ fcpw,
        const float* __restrict__ fcpb, float* __restrict__ rowbuf)
{
    if (nsurv[0] != 0) return;
    int c = blockIdx.x * 4 + (threadIdx.x >> 6);
    int lane = threadIdx.x & 63;
    const float* wr = fcpw + (size_t)c * (4*C_);
    float s = 0.f;
    for (int k = lane; k < 4*C_; k += 64) s += abuf[k] * wr[k];
    #pragma unroll
    for (int off = 32; off > 0; off >>= 1) s += __shfl_down(s, off, 64);
    if (lane == 0) rowbuf[c] = fcpb[c] + s;
}

__global__ __launch_bounds__(256) void ap_bcast(const int* __restrict__ nsurv,
        const float* __restrict__ rowbuf, float* __restrict__ out_x)
{
    if (nsurv[0] != 0) return;
    int r = blockIdx.x;
    float4 v = ((const float4*)rowbuf)[threadIdx.x];
    ((float4*)(out_x + (size_t)r * C_))[threadIdx.x] = v;
}

extern "C" void kernel_launch(void* const* d_in, const int* in_sizes, int n_in,
                              void* d_out, int out_size, void* d_ws, size_t ws_size,
                              hipStream_t stream) {
    const float* x       = (const float*)d_in[0];
    const float* amask   = (const float*)d_in[1];
    const float* prot    = (const float*)d_in[2];
    const float* ln1w    = (const float*)d_in[3];
    const float* ln1b    = (const float*)d_in[4];
    const float* cattn_w = (const float*)d_in[5];
    const float* cattn_b = (const float*)d_in[6];
    const float* cproj_w = (const float*)d_in[7];
    const float* cproj_b = (const float*)d_in[8];
    const float* ln2w    = (const float*)d_in[9];
    const float* ln2b    = (const float*)d_in[10];
    const float* fcw     = (const float*)d_in[11];
    const float* fcb     = (const float*)d_in[12];
    const float* fcpw    = (const float*)d_in[13];
    const float* fcpb    = (const float*)d_in[14];
    const float* thr     = (const float*)d_in[15];

    unsigned short* wqkv  = (unsigned short*)d_ws;
    unsigned short* wproj = wqkv  + (size_t)3*C_*C_;
    unsigned short* wfc   = wproj + (size_t)C_*C_;
    unsigned short* wfcp  = wfc   + (size_t)4*C_*C_;
    unsigned short* hbuf  = wfcp  + (size_t)4*C_*C_;
    unsigned short* qh    = hbuf  + (size_t)NROWS*C_;
    unsigned short* kh    = qh    + (size_t)NROWS*C_;
    unsigned short* vh    = kh    + (size_t)NROWS*C_;
    unsigned short* cbuf  = qh;                        // fc chunk out (dense path)
    float* imp    = (float*)(vh + (size_t)NROWS*C_);
    int*   nsurv  = (int*)(imp + NROWS);
    float* abuf   = (float*)(nsurv + 4);
    float* rowbuf = abuf + 4*C_;

    float* out_x    = (float*)d_out;
    float* out_mask = out_x + (size_t)NROWS*C_;
    float* out_loss = out_mask + NROWS;

    hipLaunchKernelGGL(zero_kernel, dim3((NROWS+8+255)/256), dim3(256), 0, stream,
                       imp, NROWS + 4);
    hipLaunchKernelGGL(cvt_bf16, dim3(3*C_*C_/4/256), dim3(256), 0, stream,
                       cattn_w, wqkv, 3*C_*C_/4, nullptr);
    hipLaunchKernelGGL(ln_bf16, dim3(NROWS), dim3(256), 0, stream, x, ln1w, ln1b, hbuf, nullptr);
    // QK GEMM (N = 2048) -> qh/kh head-major
    hipLaunchKernelGGL((gemm_bf16<3>), dim3(2048/128, NROWS/128), dim3(256), 0, stream,
                       hbuf, wqkv, cattn_b, nullptr, nullptr, nullptr,
                       C_, C_, C_, 0, 0, nullptr, qh, kh, vh, nullptr);
    // importance-only attention (paired q-tiles, double-buffered)
    hipLaunchKernelGGL(attn_imp, dim3(64*16), dim3(256), 0, stream, qh, kh, amask, imp);
    hipLaunchKernelGGL(mask_finalize, dim3(NROWS/256), dim3(256), 0, stream,
                       imp, amask, prot, thr, out_mask, out_loss, nsurv);

    // ---- dense fallback path (early-exit when nsurv == 0) ----
    hipLaunchKernelGGL(cvt3_bf16, dim3(9*C_*C_/4/256), dim3(256), 0, stream,
                       cproj_w, fcw, fcpw, wproj, wfc, wfcp, nsurv);
    hipLaunchKernelGGL((gemm_bf16<3>), dim3(1024/128, NROWS/128), dim3(256), 0, stream,
                       hbuf, wqkv + (size_t)2048*C_, cattn_b + 2048, nullptr, nullptr, nullptr,
                       C_, C_, C_, 0, 2048, nullptr, qh, kh, vh, nsurv);
    hipLaunchKernelGGL(attn_full, dim3(B_*H_*(T_/64)), dim3(256), 0, stream,
                       qh, kh, vh, amask, hbuf, nsurv);
    hipLaunchKernelGGL((gemm_bf16<4>), dim3(C_/128, NROWS/128), dim3(256), 0, stream,
                       hbuf, wproj, cproj_b, x, out_x, nullptr,
                       C_, C_, C_, C_, 0, out_mask, nullptr, nullptr, nullptr, nsurv);
    hipLaunchKernelGGL(ln_bf16, dim3(NROWS), dim3(256), 0, stream, out_x, ln2w, ln2b, hbuf, nsurv);
    for (int j = 0; j < 2; j++) {
        hipLaunchKernelGGL((gemm_bf16<1>), dim3(2048/128, NROWS/128), dim3(256), 0, stream,
                           hbuf, wfc + (size_t)j*2048*C_, fcb + j*2048, nullptr, nullptr, cbuf,
                           C_, C_, C_, 2048, 0, nullptr, nullptr, nullptr, nullptr, nsurv);
        hipLaunchKernelGGL((gemm_bf16<2>), dim3(C_/128, NROWS/128), dim3(256), 0, stream,
                           cbuf, wfcp + (size_t)j*2048, (j == 0) ? fcpb : nullptr, out_x, out_x, nullptr,
                           2048, 2048, 4*C_, C_, 0, nullptr, nullptr, nullptr, nullptr, nsurv);
    }

    // ---- all-pruned fast path (early-exit when nsurv != 0) ----
    hipLaunchKernelGGL(ap_fc,    dim3(4*C_/4), dim3(256), 0, stream, nsurv, ln2b, fcw, fcb, abuf);
    hipLaunchKernelGGL(ap_fcp,   dim3(C_/4),   dim3(256), 0, stream, nsurv, abuf, fcpw, fcpb, rowbuf);
    hipLaunchKernelGGL(ap_bcast, dim3(NROWS),  dim3(256), 0, stream, nsurv, rowbuf, out_x);
}

// Round 7
// 352.446 us; speedup vs baseline: 1.1431x; 1.1431x over previous
//
#include <hip/hip_runtime.h>
#include <math.h>

#define B_ 4
#define T_ 2048
#define C_ 1024
#define H_ 16
#define NROWS (B_*T_)   // 8192

typedef short s8v  __attribute__((ext_vector_type(8)));
typedef float f4v  __attribute__((ext_vector_type(4)));
typedef unsigned short u16v4 __attribute__((ext_vector_type(4)));

static __device__ __forceinline__ unsigned short f2bf(float x) {
    unsigned u = __float_as_uint(x);
    unsigned r = u + 0x7fffu + ((u >> 16) & 1u);
    return (unsigned short)(r >> 16);
}

static __device__ __forceinline__ void gload_lds16(const void* g, void* l) {
    __builtin_amdgcn_global_load_lds(
        (const __attribute__((address_space(1))) void*)g,
        (__attribute__((address_space(3))) void*)l, 16, 0, 0);
}

// ---------------- LayerNorm -> bf16 out (one block per row of 1024) ----------------
__global__ __launch_bounds__(256) void ln_bf16(const float* __restrict__ x,
        const float* __restrict__ w, const float* __restrict__ b,
        unsigned short* __restrict__ out, const int* __restrict__ flag)
{
    if (flag && flag[0] == 0) return;
    int row = blockIdx.x;
    int tid = threadIdx.x;
    const float4* xr = (const float4*)(x + (size_t)row * C_);
    float4 v = xr[tid];
    float s  = v.x + v.y + v.z + v.w;
    float ss = v.x*v.x + v.y*v.y + v.z*v.z + v.w*v.w;
    #pragma unroll
    for (int off = 32; off > 0; off >>= 1) {
        s  += __shfl_down(s,  off, 64);
        ss += __shfl_down(ss, off, 64);
    }
    __shared__ float rs[4], rss[4];
    __shared__ float smu, srstd;
    int wave = tid >> 6, lane = tid & 63;
    if (lane == 0) { rs[wave] = s; rss[wave] = ss; }
    __syncthreads();
    if (tid == 0) {
        float S  = rs[0]+rs[1]+rs[2]+rs[3];
        float SS = rss[0]+rss[1]+rss[2]+rss[3];
        float mu = S * (1.0f/C_);
        float var = SS * (1.0f/C_) - mu*mu;
        smu = mu; srstd = rsqrtf(var + 1e-5f);
    }
    __syncthreads();
    float mu = smu, rstd = srstd;
    float4 wv = ((const float4*)w)[tid];
    float4 bv = ((const float4*)b)[tid];
    u16v4 o;
    o.x = f2bf((v.x-mu)*rstd*wv.x + bv.x);
    o.y = f2bf((v.y-mu)*rstd*wv.y + bv.y);
    o.z = f2bf((v.z-mu)*rstd*wv.z + bv.z);
    o.w = f2bf((v.w-mu)*rstd*wv.w + bv.w);
    *(u16v4*)(out + (size_t)row * C_ + tid*4) = o;
}

// ---------------- fp32 -> bf16 convert ----------------
__global__ __launch_bounds__(256) void cvt_bf16(const float* __restrict__ in,
        unsigned short* __restrict__ out, int n4, const int* __restrict__ flag)
{
    if (flag && flag[0] == 0) return;
    int i = blockIdx.x * 256 + threadIdx.x;
    if (i < n4) {
        float4 v = ((const float4*)in)[i];
        u16v4 o = { f2bf(v.x), f2bf(v.y), f2bf(v.z), f2bf(v.w) };
        *(u16v4*)(out + (size_t)i*4) = o;
    }
}

// merged flagged conversion of cproj/fc/fcproj weights (9*C*C elements total)
__global__ __launch_bounds__(256) void cvt3_bf16(
        const float* __restrict__ cprojw, const float* __restrict__ fcw,
        const float* __restrict__ fcpw,
        unsigned short* __restrict__ wproj, unsigned short* __restrict__ wfc,
        unsigned short* __restrict__ wfcp, const int* __restrict__ flag)
{
    if (flag[0] == 0) return;
    int i = blockIdx.x * 256 + threadIdx.x;   // vec4 index, < 9*C*C/4
    const int n1 = C_*C_/4;          // cproj
    const int n2 = n1 + C_*C_;       // + fc (4C*C elems = C*C vec4)
    const float* src; unsigned short* dst; int j;
    if (i < n1)      { src = cprojw; dst = wproj; j = i; }
    else if (i < n2) { src = fcw;    dst = wfc;   j = i - n1; }
    else             { src = fcpw;   dst = wfcp;  j = i - n2; }
    float4 v = ((const float4*)src)[j];
    u16v4 o = { f2bf(v.x), f2bf(v.y), f2bf(v.z), f2bf(v.w) };
    *(u16v4*)(dst + (size_t)j*4) = o;
}

__global__ void zero_kernel(float* p, int n) {
    int i = blockIdx.x * 256 + threadIdx.x;
    if (i < n) p[i] = 0.f;
}

// ---------------- bf16 MFMA GEMM: C[m,n] = sum_k A[m][k]*Bw[n][k] ----------------
// EPI: 1 = bias + exact GELU -> bf16 ; 2 = bias(opt) + fp32 residual -> fp32
//      3 = bias -> bf16 head-major qkv scatter (q section pre-scaled by 1/8)
//      4 = bias + (res + v)*cm -> fp32
template<int EPI>
__global__ __launch_bounds__(256) void gemm_bf16(
    const unsigned short* __restrict__ A,
    const unsigned short* __restrict__ Bw,
    const float* __restrict__ bias,
    const float* __restrict__ res,
    float* __restrict__ Cout, unsigned short* __restrict__ Cbf,
    int K, int lda, int ldb, int ldc, int ncoff,
    const float* __restrict__ cmv,
    unsigned short* __restrict__ qh, unsigned short* __restrict__ kh,
    unsigned short* __restrict__ vh, const int* __restrict__ flag)
{
    if (flag && flag[0] == 0) return;
    __shared__ unsigned short As[128*64];
    __shared__ unsigned short Bs[128*64];
    int tid = threadIdx.x;
    int w = tid >> 6, lane = tid & 63, quad = lane >> 4, l16 = lane & 15;
    int wr = w >> 1, wc = w & 1;
    int m0 = blockIdx.y * 128, n0 = blockIdx.x * 128;

    size_t offA[4], offB[4];
    #pragma unroll
    for (int j = 0; j < 4; j++) {
        int ci = j*256 + tid;
        int mr = ci >> 3, kcs = ci & 7;
        int kc = kcs ^ (mr & 7);
        offA[j] = (size_t)(m0 + mr) * lda + kc*8;
        offB[j] = (size_t)(n0 + mr) * ldb + kc*8;
    }

    f4v acc[4][4];
    #pragma unroll
    for (int i = 0; i < 4; i++)
        #pragma unroll
        for (int j = 0; j < 4; j++) { acc[i][j][0]=0.f; acc[i][j][1]=0.f; acc[i][j][2]=0.f; acc[i][j][3]=0.f; }

    for (int k0 = 0; k0 < K; k0 += 64) {
        __syncthreads();
        #pragma unroll
        for (int j = 0; j < 4; j++) {
            gload_lds16(A  + offA[j] + k0, &As[(j*256 + (w<<6))*8]);
            gload_lds16(Bw + offB[j] + k0, &Bs[(j*256 + (w<<6))*8]);
        }
        __syncthreads();
        #pragma unroll
        for (int c = 0; c < 2; c++) {
            s8v af[4], bf[4];
            int sw = ((c<<2) + quad) ^ (l16 & 7);
            #pragma unroll
            for (int i = 0; i < 4; i++) {
                int mr = wr*64 + i*16 + l16;
                af[i] = *(const s8v*)&As[mr*64 + sw*8];
                int nr = wc*64 + i*16 + l16;
                bf[i] = *(const s8v*)&Bs[nr*64 + sw*8];
            }
            #pragma unroll
            for (int i = 0; i < 4; i++)
                #pragma unroll
                for (int j = 0; j < 4; j++)
                    acc[i][j] = __builtin_amdgcn_mfma_f32_16x16x32_bf16(af[i], bf[j], acc[i][j], 0, 0, 0);
        }
    }

    #pragma unroll
    for (int j = 0; j < 4; j++) {
        int ncol = n0 + wc*64 + j*16 + l16;
        float bv = bias ? bias[ncol] : 0.f;
        int hh = 0, dd = 0;
        bool qsec = false;
        unsigned short* basep = nullptr;
        if (EPI == 3) {
            int ncolg = ncol + ncoff;
            int sec = ncolg >> 10;
            int hn = ncolg & 1023;
            hh = hn >> 6; dd = hn & 63;
            basep = (sec == 0) ? qh : (sec == 1) ? kh : vh;
            qsec = (sec == 0);
        }
        #pragma unroll
        for (int i = 0; i < 4; i++) {
            #pragma unroll
            for (int reg = 0; reg < 4; reg++) {
                int m = m0 + wr*64 + i*16 + quad*4 + reg;
                float v = acc[i][j][reg] + bv;
                if (EPI == 1) {
                    v = 0.5f * v * (1.0f + erff(v * 0.70710678118654752f));
                    Cbf[(size_t)m*ldc + ncol] = f2bf(v);
                } else if (EPI == 2) {
                    Cout[(size_t)m*ldc + ncol] = v + res[(size_t)m*ldc + ncol];
                } else if (EPI == 3) {
                    if (qsec) v *= 0.125f;   // fold softmax scale into Q
                    int bb = m >> 11, t = m & 2047;
                    basep[(((size_t)(bb*H_ + hh))*T_ + t)*64 + dd] = f2bf(v);
                } else if (EPI == 4) {
                    Cout[(size_t)m*ldc + ncol] = (res[(size_t)m*ldc + ncol] + v) * cmv[m];
                }
            }
        }
    }
}

// ---------------- importance-only attention ----------------
// Block = (bh, pp): q-tiles {pp, 31-pp, pp+8, 23-pp} (256 q rows) -> uniform
// 66 frag-computes/pass. One K-fragment register load (8 ds_read_b128) serves
// up to 4 q-fragments. Masks preloaded to LDS; only prefetch rides vmcnt.
__global__ __launch_bounds__(256) void attn_imp(
    const unsigned short* __restrict__ qh, const unsigned short* __restrict__ kh,
    const float* __restrict__ amask, float* __restrict__ imp)
{
    __shared__ unsigned short Ks[2][64*64];   // 16 KB
    __shared__ float msk01[2048];             // 8 KB
    __shared__ float tileAll[32];
    __shared__ float colws[2][64];

    int tid = threadIdx.x;
    int w = tid >> 6, lane = tid & 63, quad = lane >> 4, l16 = lane & 15;
    int bh = blockIdx.x & 63;
    int pp = blockIdx.x >> 6;                 // 0..7
    int b  = bh >> 4;
    int qtf[4] = { pp, 31 - pp, pp + 8, 23 - pp };
    int ntiles = 32 - pp;

    const unsigned short* qp = qh + (size_t)bh*T_*64;
    const unsigned short* kp = kh + (size_t)bh*T_*64;
    const float* amp = amask + b*T_;

    // preamble: masks -> LDS as 0/1 floats
    for (int i = tid; i < ntiles*64; i += 256)
        msk01[i] = (amp[i] != 0.f) ? 1.f : 0.f;
    if (tid < 128) colws[tid >> 6][tid & 63] = 0.f;
    __syncthreads();
    for (int t = w; t < ntiles; t += 4) {
        bool a = __all(msk01[t*64 + lane] != 0.f);
        if (lane == 0) tileAll[t] = a ? 1.f : 0.f;
    }

    // Q fragments (4 per wave)
    int q0f[4];
    s8v aQ[4][2];
    #pragma unroll
    for (int f = 0; f < 4; f++) {
        q0f[f] = qtf[f]*64 + 16*w;
        aQ[f][0] = *(const s8v*)(qp + (size_t)(q0f[f] + l16)*64 + quad*8);
        aQ[f][1] = *(const s8v*)(qp + (size_t)(q0f[f] + l16)*64 + 32 + quad*8);
    }

    int r0 = tid >> 3,         c0 = (tid & 7) ^ (r0 & 7);
    int r1 = (256 + tid) >> 3, c1 = ((256 + tid) & 7) ^ (r1 & 7);

    // ---- pass 1: row sums of exp(s) ----
    float lrow[4][4];
    #pragma unroll
    for (int f = 0; f < 4; f++)
        #pragma unroll
        for (int reg = 0; reg < 4; reg++) lrow[f][reg] = 0.f;

    gload_lds16(kp + ((size_t)r0*64 + c0*8), &Ks[0][(w*64)*8]);
    gload_lds16(kp + ((size_t)r1*64 + c1*8), &Ks[0][(256 + w*64)*8]);

    for (int it = 0; it < ntiles; ++it) {
        __syncthreads();
        if (it + 1 < ntiles) {
            int kn = (it+1)*64, bufn = (it+1) & 1;
            gload_lds16(kp + ((size_t)(kn+r0)*64 + c0*8), &Ks[bufn][(w*64)*8]);
            gload_lds16(kp + ((size_t)(kn+r1)*64 + c1*8), &Ks[bufn][(256 + w*64)*8]);
        }
        const unsigned short* ks = Ks[it & 1];
        float allm = tileAll[it];
        float mk[4];
        #pragma unroll
        for (int nt = 0; nt < 4; nt++) mk[nt] = msk01[it*64 + nt*16 + l16];
        s8v bkr[2][4];
        #pragma unroll
        for (int c = 0; c < 2; c++)
            #pragma unroll
            for (int nt = 0; nt < 4; nt++)
                bkr[c][nt] = *(const s8v*)&ks[((nt*16 + l16)*8 + ((((c<<2)+quad) ^ (l16 & 7))))*8];

        #pragma unroll
        for (int f = 0; f < 4; f++) {
            if (it > qtf[f]) continue;       // block-uniform
            f4v accS[4];
            #pragma unroll
            for (int nt = 0; nt < 4; nt++) { accS[nt][0]=0.f; accS[nt][1]=0.f; accS[nt][2]=0.f; accS[nt][3]=0.f; }
            #pragma unroll
            for (int c = 0; c < 2; c++)
                #pragma unroll
                for (int nt = 0; nt < 4; nt++)
                    accS[nt] = __builtin_amdgcn_mfma_f32_16x16x32_bf16(aQ[f][c], bkr[c][nt], accS[nt], 0, 0, 0);
            if (it < qtf[f] && allm != 0.f) {
                #pragma unroll
                for (int nt = 0; nt < 4; nt++)
                    #pragma unroll
                    for (int reg = 0; reg < 4; reg++)
                        lrow[f][reg] += __expf(accS[nt][reg]);
            } else {
                #pragma unroll
                for (int nt = 0; nt < 4; nt++) {
                    int kg = it*64 + nt*16 + l16;
                    #pragma unroll
                    for (int reg = 0; reg < 4; reg++) {
                        float me = (kg <= q0f[f] + quad*4 + reg) ? mk[nt] : 0.f;
                        lrow[f][reg] += __expf(accS[nt][reg]) * me;
                    }
                }
            }
        }
    }

    float linv[4][4];
    #pragma unroll
    for (int f = 0; f < 4; f++)
        #pragma unroll
        for (int reg = 0; reg < 4; reg++) {
            float v = lrow[f][reg];
            v += __shfl_xor(v, 1); v += __shfl_xor(v, 2);
            v += __shfl_xor(v, 4); v += __shfl_xor(v, 8);
            linv[f][reg] = (v > 0.f) ? 1.0f / v : 0.f;
        }

    // ---- pass 2: colsums of p = exp(s)/l ----
    __syncthreads();   // pass-1 reads of Ks done before re-prefetch
    gload_lds16(kp + ((size_t)r0*64 + c0*8), &Ks[0][(w*64)*8]);
    gload_lds16(kp + ((size_t)r1*64 + c1*8), &Ks[0][(256 + w*64)*8]);

    for (int it = 0; it < ntiles; ++it) {
        __syncthreads();
        if (it + 1 < ntiles) {
            int kn = (it+1)*64, bufn = (it+1) & 1;
            gload_lds16(kp + ((size_t)(kn+r0)*64 + c0*8), &Ks[bufn][(w*64)*8]);
            gload_lds16(kp + ((size_t)(kn+r1)*64 + c1*8), &Ks[bufn][(256 + w*64)*8]);
        }
        if (it > 0 && tid < 64) {            // flush other buffer: race-free
            int ob = (it-1) & 1;
            atomicAdd(&imp[b*T_ + (it-1)*64 + tid], colws[ob][tid]);
            colws[ob][tid] = 0.f;
        }
        const unsigned short* ks = Ks[it & 1];
        float allm = tileAll[it];
        float mk[4];
        #pragma unroll
        for (int nt = 0; nt < 4; nt++) mk[nt] = msk01[it*64 + nt*16 + l16];
        s8v bkr[2][4];
        #pragma unroll
        for (int c = 0; c < 2; c++)
            #pragma unroll
            for (int nt = 0; nt < 4; nt++)
                bkr[c][nt] = *(const s8v*)&ks[((nt*16 + l16)*8 + ((((c<<2)+quad) ^ (l16 & 7))))*8];

        float cs[4] = {0.f, 0.f, 0.f, 0.f};
        #pragma unroll
        for (int f = 0; f < 4; f++) {
            if (it > qtf[f]) continue;
            f4v accS[4];
            #pragma unroll
            for (int nt = 0; nt < 4; nt++) { accS[nt][0]=0.f; accS[nt][1]=0.f; accS[nt][2]=0.f; accS[nt][3]=0.f; }
            #pragma unroll
            for (int c = 0; c < 2; c++)
                #pragma unroll
                for (int nt = 0; nt < 4; nt++)
                    accS[nt] = __builtin_amdgcn_mfma_f32_16x16x32_bf16(aQ[f][c], bkr[c][nt], accS[nt], 0, 0, 0);
            if (it < qtf[f] && allm != 0.f) {
                #pragma unroll
                for (int nt = 0; nt < 4; nt++)
                    #pragma unroll
                    for (int reg = 0; reg < 4; reg++)
                        cs[nt] += __expf(accS[nt][reg]) * linv[f][reg];
            } else {
                #pragma unroll
                for (int nt = 0; nt < 4; nt++) {
                    int kg = it*64 + nt*16 + l16;
                    #pragma unroll
                    for (int reg = 0; reg < 4; reg++) {
                        float me = (kg <= q0f[f] + quad*4 + reg) ? mk[nt] : 0.f;
                        cs[nt] += __expf(accS[nt][reg]) * linv[f][reg] * me;
                    }
                }
            }
        }
        #pragma unroll
        for (int nt = 0; nt < 4; nt++) {
            float v = cs[nt];
            v += __shfl_xor(v, 16);
            v += __shfl_xor(v, 32);
            if (quad == 0) atomicAdd(&colws[it & 1][nt*16 + l16], v);
        }
    }
    __syncthreads();
    if (tid < 64) atomicAdd(&imp[b*T_ + (ntiles-1)*64 + tid], colws[(ntiles-1) & 1][tid]);
}

// ---------------- mask finalize: cm, loss, survivor count ----------------
__global__ __launch_bounds__(256) void mask_finalize(
    const float* __restrict__ imp, const float* __restrict__ amask,
    const float* __restrict__ prot, const float* __restrict__ thr,
    float* __restrict__ mask_out, float* __restrict__ loss_out,
    int* __restrict__ nsurv)
{
    int i = blockIdx.x * 256 + threadIdx.x;
    float impv = imp[i] * (1.0f / (float)(H_ * T_));
    float pm = (impv >= thr[0]) ? 1.f : 0.f;
    if (prot[i] > 0.f) pm = 1.f;
    float cm = amask[i] * pm;
    mask_out[i] = cm;
    if (i == 0) loss_out[0] = 0.f;
    unsigned long long bal = __ballot(cm != 0.f);
    int cnt = __popcll(bal);
    __shared__ int bs;
    if (threadIdx.x == 0) bs = 0;
    __syncthreads();
    if ((threadIdx.x & 63) == 0 && cnt) atomicAdd(&bs, cnt);
    __syncthreads();
    if (threadIdx.x == 0 && bs) atomicAdd(nsurv, bs);
}

// ---------------- full attention (dense fallback; Q pre-scaled) ----------------
__global__ __launch_bounds__(256) void attn_full(
    const unsigned short* __restrict__ qh, const unsigned short* __restrict__ kh,
    const unsigned short* __restrict__ vh, const float* __restrict__ amask,
    unsigned short* __restrict__ y, const int* __restrict__ flag)
{
    if (flag[0] == 0) return;
    __shared__ unsigned short Ks[64][72];
    __shared__ unsigned short Vt[64][72];
    __shared__ unsigned short Ps[4][16][72];
    __shared__ float mks[64];

    int tid = threadIdx.x;
    int w = tid >> 6, lane = tid & 63, quad = lane >> 4, l16 = lane & 15;
    int nqt = T_ / 64;
    int qt = blockIdx.x % nqt;
    int bh = blockIdx.x / nqt;
    int b = bh >> 4, h = bh & 15;
    int q0 = qt * 64;

    const unsigned short* qp = qh + (size_t)bh * T_ * 64;
    const unsigned short* kp = kh + (size_t)bh * T_ * 64;
    const unsigned short* vp = vh + (size_t)bh * T_ * 64;

    int qrow = q0 + 16*w + l16;
    s8v aQ0 = *(const s8v*)(qp + (size_t)qrow*64 + quad*8);
    s8v aQ1 = *(const s8v*)(qp + (size_t)qrow*64 + 32 + quad*8);

    int qwmax = q0 + 16*w + 15;
    int ntiles = qt + 1;
    int qg = q0 + 16*w + quad*4;

    float lrow[4] = {0.f, 0.f, 0.f, 0.f};
    for (int it = 0; it < ntiles; ++it) {
        int k0 = it * 64;
        __syncthreads();
        for (int cid = tid; cid < 512; cid += 256) {
            int row = cid >> 3, ch = cid & 7;
            *(s8v*)&Ks[row][ch*8] = *(const s8v*)(kp + (size_t)(k0+row)*64 + ch*8);
        }
        if (tid < 64) mks[tid] = amask[b*T_ + k0 + tid];
        __syncthreads();
        if (k0 > qwmax) continue;
        f4v accS[4];
        #pragma unroll
        for (int nt = 0; nt < 4; nt++) { accS[nt][0]=0.f; accS[nt][1]=0.f; accS[nt][2]=0.f; accS[nt][3]=0.f; }
        #pragma unroll
        for (int nt = 0; nt < 4; nt++) {
            s8v b0 = *(const s8v*)&Ks[nt*16 + l16][quad*8];
            s8v b1 = *(const s8v*)&Ks[nt*16 + l16][32 + quad*8];
            accS[nt] = __builtin_amdgcn_mfma_f32_16x16x32_bf16(aQ0, b0, accS[nt], 0, 0, 0);
            accS[nt] = __builtin_amdgcn_mfma_f32_16x16x32_bf16(aQ1, b1, accS[nt], 0, 0, 0);
        }
        #pragma unroll
        for (int nt = 0; nt < 4; nt++) {
            int kg = k0 + nt*16 + l16;
            float mkv = mks[nt*16 + l16];
            #pragma unroll
            for (int reg = 0; reg < 4; reg++) {
                bool val = (kg <= qg + reg) && (mkv != 0.f);
                float e = __expf(accS[nt][reg]);
                lrow[reg] += val ? e : 0.f;
            }
        }
    }
    float linv[4];
    #pragma unroll
    for (int reg = 0; reg < 4; reg++) {
        float v = lrow[reg];
        v += __shfl_xor(v, 1); v += __shfl_xor(v, 2);
        v += __shfl_xor(v, 4); v += __shfl_xor(v, 8);
        linv[reg] = (v > 0.f) ? 1.0f / v : 0.f;
    }

    f4v accO[4];
    #pragma unroll
    for (int nt = 0; nt < 4; nt++) { accO[nt][0]=0.f; accO[nt][1]=0.f; accO[nt][2]=0.f; accO[nt][3]=0.f; }

    for (int it = 0; it < ntiles; ++it) {
        int k0 = it * 64;
        __syncthreads();
        for (int cid = tid; cid < 512; cid += 256) {
            int row = cid >> 3, ch = cid & 7;
            s8v kv = *(const s8v*)(kp + (size_t)(k0+row)*64 + ch*8);
            *(s8v*)&Ks[row][ch*8] = kv;
            s8v vv = *(const s8v*)(vp + (size_t)(k0+row)*64 + ch*8);
            #pragma unroll
            for (int j = 0; j < 8; j++) Vt[ch*8 + j][row] = (unsigned short)vv[j];
        }
        if (tid < 64) mks[tid] = amask[b*T_ + k0 + tid];
        __syncthreads();
        if (k0 > qwmax) continue;
        f4v accS[4];
        #pragma unroll
        for (int nt = 0; nt < 4; nt++) { accS[nt][0]=0.f; accS[nt][1]=0.f; accS[nt][2]=0.f; accS[nt][3]=0.f; }
        #pragma unroll
        for (int nt = 0; nt < 4; nt++) {
            s8v b0 = *(const s8v*)&Ks[nt*16 + l16][quad*8];
            s8v b1 = *(const s8v*)&Ks[nt*16 + l16][32 + quad*8];
            accS[nt] = __builtin_amdgcn_mfma_f32_16x16x32_bf16(aQ0, b0, accS[nt], 0, 0, 0);
            accS[nt] = __builtin_amdgcn_mfma_f32_16x16x32_bf16(aQ1, b1, accS[nt], 0, 0, 0);
        }
        #pragma unroll
        for (int nt = 0; nt < 4; nt++) {
            int kg = k0 + nt*16 + l16;
            float mkv = mks[nt*16 + l16];
            #pragma unroll
            for (int reg = 0; reg < 4; reg++) {
                bool val = (kg <= qg + reg) && (mkv != 0.f);
                float p = val ? __expf(accS[nt][reg]) * linv[reg] : 0.f;
                Ps[w][quad*4 + reg][nt*16 + l16] = f2bf(p);
            }
        }
        s8v aP0 = *(const s8v*)&Ps[w][l16][quad*8];
        s8v aP1 = *(const s8v*)&Ps[w][l16][32 + quad*8];
        #pragma unroll
        for (int nt = 0; nt < 4; nt++) {
            s8v bv0 = *(const s8v*)&Vt[nt*16 + l16][quad*8];
            s8v bv1 = *(const s8v*)&Vt[nt*16 + l16][32 + quad*8];
            accO[nt] = __builtin_amdgcn_mfma_f32_16x16x32_bf16(aP0, bv0, accO[nt], 0, 0, 0);
            accO[nt] = __builtin_amdgcn_mfma_f32_16x16x32_bf16(aP1, bv1, accO[nt], 0, 0, 0);
        }
    }
    #pragma unroll
    for (int nt = 0; nt < 4; nt++) {
        #pragma unroll
        for (int reg = 0; reg < 4; reg++) {
            int q = q0 + 16*w + quad*4 + reg;
            y[((size_t)(b*T_ + q))*C_ + h*64 + nt*16 + l16] = f2bf(accO[nt][reg]);
        }
    }
}

// ---------------- all-pruned fast path: one-row MLP + broadcast ----------------
__global__ __launch_bounds__(256) void ap_fc(const int* __restrict__ nsurv,
        const float* __restrict__ ln2b, const float* __restrict__ fcw,
        const float* __restrict__ fcb, float* __restrict__ abuf)
{
    if (nsurv[0] != 0) return;
    int j = blockIdx.x * 4 + (threadIdx.x >> 6);
    int lane = threadIdx.x & 63;
    const float* wr = fcw + (size_t)j * C_;
    float s = 0.f;
    for (int k = lane; k < C_; k += 64) s += ln2b[k] * wr[k];
    #pragma unroll
    for (int off = 32; off > 0; off >>= 1) s += __shfl_down(s, off, 64);
    if (lane == 0) {
        float v = fcb[j] + s;
        abuf[j] = 0.5f * v * (1.0f + erff(v * 0.70710678118654752f));
    }
}

__global__ __launch_bounds__(256) void ap_fcp(const int* __restrict__ nsurv,
        const float* __restrict__ abuf, const float* __restrict__ fcpw,
        const float* __restrict__ fcpb, float* __restrict__ rowbuf)
{
    if (nsurv[0] != 0) return;
    int c = blockIdx.x * 4 + (threadIdx.x >> 6);
    int lane = threadIdx.x & 63;
    const float* wr = fcpw + (size_t)c * (4*C_);
    float s = 0.f;
    for (int k = lane; k < 4*C_; k += 64) s += abuf[k] * wr[k];
    #pragma unroll
    for (int off = 32; off > 0; off >>= 1) s += __shfl_down(s, off, 64);
    if (lane == 0) rowbuf[c] = fcpb[c] + s;
}

__global__ __launch_bounds__(256) void ap_bcast(const int* __restrict__ nsurv,
        const float* __restrict__ rowbuf, float* __restrict__ out_x)
{
    if (nsurv[0] != 0) return;
    int r = blockIdx.x;
    float4 v = ((const float4*)rowbuf)[threadIdx.x];
    ((float4*)(out_x + (size_t)r * C_))[threadIdx.x] = v;
}

extern "C" void kernel_launch(void* const* d_in, const int* in_sizes, int n_in,
                              void* d_out, int out_size, void* d_ws, size_t ws_size,
                              hipStream_t stream) {
    const float* x       = (const float*)d_in[0];
    const float* amask   = (const float*)d_in[1];
    const float* prot    = (const float*)d_in[2];
    const float* ln1w    = (const float*)d_in[3];
    const float* ln1b    = (const float*)d_in[4];
    const float* cattn_w = (const float*)d_in[5];
    const float* cattn_b = (const float*)d_in[6];
    const float* cproj_w = (const float*)d_in[7];
    const float* cproj_b = (const float*)d_in[8];
    const float* ln2w    = (const float*)d_in[9];
    const float* ln2b    = (const float*)d_in[10];
    const float* fcw     = (const float*)d_in[11];
    const float* fcb     = (const float*)d_in[12];
    const float* fcpw    = (const float*)d_in[13];
    const float* fcpb    = (const float*)d_in[14];
    const float* thr     = (const float*)d_in[15];

    unsigned short* wqkv  = (unsigned short*)d_ws;
    unsigned short* wproj = wqkv  + (size_t)3*C_*C_;
    unsigned short* wfc   = wproj + (size_t)C_*C_;
    unsigned short* wfcp  = wfc   + (size_t)4*C_*C_;
    unsigned short* hbuf  = wfcp  + (size_t)4*C_*C_;
    unsigned short* qh    = hbuf  + (size_t)NROWS*C_;
    unsigned short* kh    = qh    + (size_t)NROWS*C_;
    unsigned short* vh    = kh    + (size_t)NROWS*C_;
    unsigned short* cbuf  = qh;                        // fc chunk out (dense path)
    float* imp    = (float*)(vh + (size_t)NROWS*C_);
    int*   nsurv  = (int*)(imp + NROWS);
    float* abuf   = (float*)(nsurv + 4);
    float* rowbuf = abuf + 4*C_;

    float* out_x    = (float*)d_out;
    float* out_mask = out_x + (size_t)NROWS*C_;
    float* out_loss = out_mask + NROWS;

    hipLaunchKernelGGL(zero_kernel, dim3((NROWS+8+255)/256), dim3(256), 0, stream,
                       imp, NROWS + 4);
    hipLaunchKernelGGL(cvt_bf16, dim3(3*C_*C_/4/256), dim3(256), 0, stream,
                       cattn_w, wqkv, 3*C_*C_/4, nullptr);
    hipLaunchKernelGGL(ln_bf16, dim3(NROWS), dim3(256), 0, stream, x, ln1w, ln1b, hbuf, nullptr);
    // QK GEMM (N = 2048) -> qh/kh head-major (q pre-scaled by 1/8)
    hipLaunchKernelGGL((gemm_bf16<3>), dim3(2048/128, NROWS/128), dim3(256), 0, stream,
                       hbuf, wqkv, cattn_b, nullptr, nullptr, nullptr,
                       C_, C_, C_, 0, 0, nullptr, qh, kh, vh, nullptr);
    // importance-only attention (4 q-tiles/block, shared K fragments)
    hipLaunchKernelGGL(attn_imp, dim3(64*8), dim3(256), 0, stream, qh, kh, amask, imp);
    hipLaunchKernelGGL(mask_finalize, dim3(NROWS/256), dim3(256), 0, stream,
                       imp, amask, prot, thr, out_mask, out_loss, nsurv);

    // ---- dense fallback path (early-exit when nsurv == 0) ----
    hipLaunchKernelGGL(cvt3_bf16, dim3(9*C_*C_/4/256), dim3(256), 0, stream,
                       cproj_w, fcw, fcpw, wproj, wfc, wfcp, nsurv);
    hipLaunchKernelGGL((gemm_bf16<3>), dim3(1024/128, NROWS/128), dim3(256), 0, stream,
                       hbuf, wqkv + (size_t)2048*C_, cattn_b + 2048, nullptr, nullptr, nullptr,
                       C_, C_, C_, 0, 2048, nullptr, qh, kh, vh, nsurv);
    hipLaunchKernelGGL(attn_full, dim3(B_*H_*(T_/64)), dim3(256), 0, stream,
                       qh, kh, vh, amask, hbuf, nsurv);
    hipLaunchKernelGGL((gemm_bf16<4>), dim3(C_/128, NROWS/128), dim3(256), 0, stream,
                       hbuf, wproj, cproj_b, x, out_x, nullptr,
                       C_, C_, C_, C_, 0, out_mask, nullptr, nullptr, nullptr, nsurv);
    hipLaunchKernelGGL(ln_bf16, dim3(NROWS), dim3(256), 0, stream, out_x, ln2w, ln2b, hbuf, nsurv);
    for (int j = 0; j < 2; j++) {
        hipLaunchKernelGGL((gemm_bf16<1>), dim3(2048/128, NROWS/128), dim3(256), 0, stream,
                           hbuf, wfc + (size_t)j*2048*C_, fcb + j*2048, nullptr, nullptr, cbuf,
                           C_, C_, C_, 2048, 0, nullptr, nullptr, nullptr, nullptr, nsurv);
        hipLaunchKernelGGL((gemm_bf16<2>), dim3(C_/128, NROWS/128), dim3(256), 0, stream,
                           cbuf, wfcp + (size_t)j*2048, (j == 0) ? fcpb : nullptr, out_x, out_x, nullptr,
                           2048, 2048, 4*C_, C_, 0, nullptr, nullptr, nullptr, nullptr, nsurv);
    }

    // ---- all-pruned fast path (early-exit when nsurv != 0) ----
    hipLaunchKernelGGL(ap_fc,    dim3(4*C_/4), dim3(256), 0, stream, nsurv, ln2b, fcw, fcb, abuf);
    hipLaunchKernelGGL(ap_fcp,   dim3(C_/4),   dim3(256), 0, stream, nsurv, abuf, fcpw, fcpb, rowbuf);
    hipLaunchKernelGGL(ap_bcast, dim3(NROWS),  dim3(256), 0, stream, nsurv, rowbuf, out_x);
}

// Round 8
// 348.178 us; speedup vs baseline: 1.1572x; 1.0123x over previous
//
#include <hip/hip_runtime.h>
#include <math.h>

#define B_ 4
#define T_ 2048
#define C_ 1024
#define H_ 16
#define NROWS (B_*T_)   // 8192

typedef short s8v  __attribute__((ext_vector_type(8)));
typedef float f4v  __attribute__((ext_vector_type(4)));
typedef unsigned short u16v4 __attribute__((ext_vector_type(4)));

#define QSCALE 0.1803368801111f   // 0.125 * log2(e): scores become log2-domain

static __device__ __forceinline__ unsigned short f2bf(float x) {
    unsigned u = __float_as_uint(x);
    unsigned r = u + 0x7fffu + ((u >> 16) & 1u);
    return (unsigned short)(r >> 16);
}

static __device__ __forceinline__ float fexp2(float x) {
    return __builtin_amdgcn_exp2f(x);
}

static __device__ __forceinline__ void gload_lds16(const void* g, void* l) {
    __builtin_amdgcn_global_load_lds(
        (const __attribute__((address_space(1))) void*)g,
        (__attribute__((address_space(3))) void*)l, 16, 0, 0);
}

// ---------------- LayerNorm -> bf16 out (one block per row of 1024) ----------------
__global__ __launch_bounds__(256) void ln_bf16(const float* __restrict__ x,
        const float* __restrict__ w, const float* __restrict__ b,
        unsigned short* __restrict__ out, const int* __restrict__ flag)
{
    if (flag && flag[0] == 0) return;
    int row = blockIdx.x;
    int tid = threadIdx.x;
    const float4* xr = (const float4*)(x + (size_t)row * C_);
    float4 v = xr[tid];
    float s  = v.x + v.y + v.z + v.w;
    float ss = v.x*v.x + v.y*v.y + v.z*v.z + v.w*v.w;
    #pragma unroll
    for (int off = 32; off > 0; off >>= 1) {
        s  += __shfl_down(s,  off, 64);
        ss += __shfl_down(ss, off, 64);
    }
    __shared__ float rs[4], rss[4];
    __shared__ float smu, srstd;
    int wave = tid >> 6, lane = tid & 63;
    if (lane == 0) { rs[wave] = s; rss[wave] = ss; }
    __syncthreads();
    if (tid == 0) {
        float S  = rs[0]+rs[1]+rs[2]+rs[3];
        float SS = rss[0]+rss[1]+rss[2]+rss[3];
        float mu = S * (1.0f/C_);
        float var = SS * (1.0f/C_) - mu*mu;
        smu = mu; srstd = rsqrtf(var + 1e-5f);
    }
    __syncthreads();
    float mu = smu, rstd = srstd;
    float4 wv = ((const float4*)w)[tid];
    float4 bv = ((const float4*)b)[tid];
    u16v4 o;
    o.x = f2bf((v.x-mu)*rstd*wv.x + bv.x);
    o.y = f2bf((v.y-mu)*rstd*wv.y + bv.y);
    o.z = f2bf((v.z-mu)*rstd*wv.z + bv.z);
    o.w = f2bf((v.w-mu)*rstd*wv.w + bv.w);
    *(u16v4*)(out + (size_t)row * C_ + tid*4) = o;
}

// ---------------- fp32 -> bf16 convert ----------------
__global__ __launch_bounds__(256) void cvt_bf16(const float* __restrict__ in,
        unsigned short* __restrict__ out, int n4, const int* __restrict__ flag)
{
    if (flag && flag[0] == 0) return;
    int i = blockIdx.x * 256 + threadIdx.x;
    if (i < n4) {
        float4 v = ((const float4*)in)[i];
        u16v4 o = { f2bf(v.x), f2bf(v.y), f2bf(v.z), f2bf(v.w) };
        *(u16v4*)(out + (size_t)i*4) = o;
    }
}

// merged flagged conversion of cproj/fc/fcproj weights (9*C*C elements total)
__global__ __launch_bounds__(256) void cvt3_bf16(
        const float* __restrict__ cprojw, const float* __restrict__ fcw,
        const float* __restrict__ fcpw,
        unsigned short* __restrict__ wproj, unsigned short* __restrict__ wfc,
        unsigned short* __restrict__ wfcp, const int* __restrict__ flag)
{
    if (flag[0] == 0) return;
    int i = blockIdx.x * 256 + threadIdx.x;   // vec4 index, < 9*C*C/4
    const int n1 = C_*C_/4;          // cproj
    const int n2 = n1 + C_*C_;       // + fc (4C*C elems = C*C vec4)
    const float* src; unsigned short* dst; int j;
    if (i < n1)      { src = cprojw; dst = wproj; j = i; }
    else if (i < n2) { src = fcw;    dst = wfc;   j = i - n1; }
    else             { src = fcpw;   dst = wfcp;  j = i - n2; }
    float4 v = ((const float4*)src)[j];
    u16v4 o = { f2bf(v.x), f2bf(v.y), f2bf(v.z), f2bf(v.w) };
    *(u16v4*)(dst + (size_t)j*4) = o;
}

__global__ void zero_kernel(float* p, int n) {
    int i = blockIdx.x * 256 + threadIdx.x;
    if (i < n) p[i] = 0.f;
}

// ---------------- bf16 MFMA GEMM: C[m,n] = sum_k A[m][k]*Bw[n][k] ----------------
// EPI: 1 = bias + exact GELU -> bf16 ; 2 = bias(opt) + fp32 residual -> fp32
//      3 = bias -> bf16 head-major qkv scatter (q section pre-scaled by QSCALE)
//      4 = bias + (res + v)*cm -> fp32
template<int EPI>
__global__ __launch_bounds__(256) void gemm_bf16(
    const unsigned short* __restrict__ A,
    const unsigned short* __restrict__ Bw,
    const float* __restrict__ bias,
    const float* __restrict__ res,
    float* __restrict__ Cout, unsigned short* __restrict__ Cbf,
    int K, int lda, int ldb, int ldc, int ncoff,
    const float* __restrict__ cmv,
    unsigned short* __restrict__ qh, unsigned short* __restrict__ kh,
    unsigned short* __restrict__ vh, const int* __restrict__ flag)
{
    if (flag && flag[0] == 0) return;
    __shared__ unsigned short As[128*64];
    __shared__ unsigned short Bs[128*64];
    int tid = threadIdx.x;
    int w = tid >> 6, lane = tid & 63, quad = lane >> 4, l16 = lane & 15;
    int wr = w >> 1, wc = w & 1;
    int m0 = blockIdx.y * 128, n0 = blockIdx.x * 128;

    size_t offA[4], offB[4];
    #pragma unroll
    for (int j = 0; j < 4; j++) {
        int ci = j*256 + tid;
        int mr = ci >> 3, kcs = ci & 7;
        int kc = kcs ^ (mr & 7);
        offA[j] = (size_t)(m0 + mr) * lda + kc*8;
        offB[j] = (size_t)(n0 + mr) * ldb + kc*8;
    }

    f4v acc[4][4];
    #pragma unroll
    for (int i = 0; i < 4; i++)
        #pragma unroll
        for (int j = 0; j < 4; j++) { acc[i][j][0]=0.f; acc[i][j][1]=0.f; acc[i][j][2]=0.f; acc[i][j][3]=0.f; }

    for (int k0 = 0; k0 < K; k0 += 64) {
        __syncthreads();
        #pragma unroll
        for (int j = 0; j < 4; j++) {
            gload_lds16(A  + offA[j] + k0, &As[(j*256 + (w<<6))*8]);
            gload_lds16(Bw + offB[j] + k0, &Bs[(j*256 + (w<<6))*8]);
        }
        __syncthreads();
        #pragma unroll
        for (int c = 0; c < 2; c++) {
            s8v af[4], bf[4];
            int sw = ((c<<2) + quad) ^ (l16 & 7);
            #pragma unroll
            for (int i = 0; i < 4; i++) {
                int mr = wr*64 + i*16 + l16;
                af[i] = *(const s8v*)&As[mr*64 + sw*8];
                int nr = wc*64 + i*16 + l16;
                bf[i] = *(const s8v*)&Bs[nr*64 + sw*8];
            }
            #pragma unroll
            for (int i = 0; i < 4; i++)
                #pragma unroll
                for (int j = 0; j < 4; j++)
                    acc[i][j] = __builtin_amdgcn_mfma_f32_16x16x32_bf16(af[i], bf[j], acc[i][j], 0, 0, 0);
        }
    }

    #pragma unroll
    for (int j = 0; j < 4; j++) {
        int ncol = n0 + wc*64 + j*16 + l16;
        float bv = bias ? bias[ncol] : 0.f;
        int hh = 0, dd = 0;
        bool qsec = false;
        unsigned short* basep = nullptr;
        if (EPI == 3) {
            int ncolg = ncol + ncoff;
            int sec = ncolg >> 10;
            int hn = ncolg & 1023;
            hh = hn >> 6; dd = hn & 63;
            basep = (sec == 0) ? qh : (sec == 1) ? kh : vh;
            qsec = (sec == 0);
        }
        #pragma unroll
        for (int i = 0; i < 4; i++) {
            #pragma unroll
            for (int reg = 0; reg < 4; reg++) {
                int m = m0 + wr*64 + i*16 + quad*4 + reg;
                float v = acc[i][j][reg] + bv;
                if (EPI == 1) {
                    v = 0.5f * v * (1.0f + erff(v * 0.70710678118654752f));
                    Cbf[(size_t)m*ldc + ncol] = f2bf(v);
                } else if (EPI == 2) {
                    Cout[(size_t)m*ldc + ncol] = v + res[(size_t)m*ldc + ncol];
                } else if (EPI == 3) {
                    if (qsec) v *= QSCALE;   // fold softmax scale + log2(e) into Q
                    int bb = m >> 11, t = m & 2047;
                    basep[(((size_t)(bb*H_ + hh))*T_ + t)*64 + dd] = f2bf(v);
                } else if (EPI == 4) {
                    Cout[(size_t)m*ldc + ncol] = (res[(size_t)m*ldc + ncol] + v) * cmv[m];
                }
            }
        }
    }
}

// ---------------- attention pass 1: linv[bh][q] = 1/sum_k exp(s) ----------------
// Block = (qt heavy-first, bh): 64 q-rows; 4 waves split the causal k-tiles.
// K fragments loaded global->registers; NO barrier in the loop.
__global__ __launch_bounds__(256) void attn_rowsum(
    const unsigned short* __restrict__ qh, const unsigned short* __restrict__ kh,
    const float* __restrict__ amask, float* __restrict__ linvbuf)
{
    __shared__ float msk01[2048];
    __shared__ float lred[4][64];

    int tid = threadIdx.x;
    int w = tid >> 6, lane = tid & 63, quad = lane >> 4, l16 = lane & 15;
    int qt = 31 - (blockIdx.x >> 6);     // heavy blocks dispatched first
    int bh = blockIdx.x & 63;
    int b  = bh >> 4;
    int q0 = qt * 64;
    int ntiles = qt + 1;

    const unsigned short* qp = qh + (size_t)bh*T_*64;
    const unsigned short* kp = kh + (size_t)bh*T_*64;
    const float* amp = amask + b*T_;

    for (int i = tid; i < ntiles*64; i += 256)
        msk01[i] = (amp[i] != 0.f) ? 1.f : 0.f;
    __syncthreads();

    // Q fragments: 4 x 16 rows
    s8v aQ[4][2];
    #pragma unroll
    for (int qf = 0; qf < 4; qf++) {
        int row = q0 + qf*16 + l16;
        aQ[qf][0] = *(const s8v*)(qp + (size_t)row*64 + quad*8);
        aQ[qf][1] = *(const s8v*)(qp + (size_t)row*64 + 32 + quad*8);
    }

    float lrow[4][4];
    #pragma unroll
    for (int qf = 0; qf < 4; qf++)
        #pragma unroll
        for (int reg = 0; reg < 4; reg++) lrow[qf][reg] = 0.f;

    for (int it = w; it < ntiles; it += 4) {
        int k0 = it * 64;
        s8v bk[2][4];
        #pragma unroll
        for (int c = 0; c < 2; c++)
            #pragma unroll
            for (int nt = 0; nt < 4; nt++)
                bk[c][nt] = *(const s8v*)(kp + (size_t)(k0 + nt*16 + l16)*64 + c*32 + quad*8);
        float mk[4];
        #pragma unroll
        for (int nt = 0; nt < 4; nt++) mk[nt] = msk01[k0 + nt*16 + l16];
        bool allm = __all(mk[0] != 0.f && mk[1] != 0.f && mk[2] != 0.f && mk[3] != 0.f);

        #pragma unroll
        for (int qf = 0; qf < 4; qf++) {
            f4v acc[4];
            #pragma unroll
            for (int nt = 0; nt < 4; nt++) { acc[nt][0]=0.f; acc[nt][1]=0.f; acc[nt][2]=0.f; acc[nt][3]=0.f; }
            #pragma unroll
            for (int c = 0; c < 2; c++)
                #pragma unroll
                for (int nt = 0; nt < 4; nt++)
                    acc[nt] = __builtin_amdgcn_mfma_f32_16x16x32_bf16(aQ[qf][c], bk[c][nt], acc[nt], 0, 0, 0);
            if (it < qt && allm) {
                #pragma unroll
                for (int nt = 0; nt < 4; nt++)
                    #pragma unroll
                    for (int reg = 0; reg < 4; reg++)
                        lrow[qf][reg] += fexp2(acc[nt][reg]);
            } else if (it < qt) {
                #pragma unroll
                for (int nt = 0; nt < 4; nt++)
                    #pragma unroll
                    for (int reg = 0; reg < 4; reg++)
                        lrow[qf][reg] += fexp2(acc[nt][reg]) * mk[nt];
            } else {   // diagonal tile
                #pragma unroll
                for (int nt = 0; nt < 4; nt++) {
                    int kg = k0 + nt*16 + l16;
                    #pragma unroll
                    for (int reg = 0; reg < 4; reg++) {
                        float me = (kg <= q0 + qf*16 + quad*4 + reg) ? mk[nt] : 0.f;
                        lrow[qf][reg] += fexp2(acc[nt][reg]) * me;
                    }
                }
            }
        }
    }

    // reduce over the 16 column-lanes (l16 bits)
    #pragma unroll
    for (int qf = 0; qf < 4; qf++)
        #pragma unroll
        for (int reg = 0; reg < 4; reg++) {
            float v = lrow[qf][reg];
            v += __shfl_xor(v, 1); v += __shfl_xor(v, 2);
            v += __shfl_xor(v, 4); v += __shfl_xor(v, 8);
            lrow[qf][reg] = v;
        }
    if (l16 == 0) {
        #pragma unroll
        for (int qf = 0; qf < 4; qf++)
            #pragma unroll
            for (int reg = 0; reg < 4; reg++)
                lred[w][qf*16 + quad*4 + reg] = lrow[qf][reg];
    }
    __syncthreads();
    if (tid < 64) {
        float t = lred[0][tid] + lred[1][tid] + lred[2][tid] + lred[3][tid];
        linvbuf[(size_t)bh*T_ + q0 + tid] = (t > 0.f) ? 1.0f / t : 0.f;
    }
}

// ---------------- attention pass 2: imp[b][k] += sum_{h,q} exp(s)*linv ----------------
// Block = (kc heavy-first, bh): 64 key-cols; K fragments resident in registers;
// 4 waves split the q-tiles qt >= kc. NO barrier in the loop.
__global__ __launch_bounds__(256) void attn_colsum(
    const unsigned short* __restrict__ qh, const unsigned short* __restrict__ kh,
    const float* __restrict__ amask, const float* __restrict__ linvbuf,
    float* __restrict__ imp)
{
    __shared__ float cred[4][64];

    int tid = threadIdx.x;
    int w = tid >> 6, lane = tid & 63, quad = lane >> 4, l16 = lane & 15;
    int kc = blockIdx.x >> 6;            // low kc = heavy, dispatched first
    int bh = blockIdx.x & 63;
    int b  = bh >> 4;
    int k0 = kc * 64;

    const unsigned short* qp = qh + (size_t)bh*T_*64;
    const unsigned short* kp = kh + (size_t)bh*T_*64;
    const float* lp = linvbuf + (size_t)bh*T_;

    // persistent K fragments + key mask
    s8v bk[2][4];
    float mk[4];
    #pragma unroll
    for (int nt = 0; nt < 4; nt++) {
        int key = k0 + nt*16 + l16;
        bk[0][nt] = *(const s8v*)(kp + (size_t)key*64 + quad*8);
        bk[1][nt] = *(const s8v*)(kp + (size_t)key*64 + 32 + quad*8);
        mk[nt] = amask[b*T_ + key];
    }

    float cs[4] = {0.f, 0.f, 0.f, 0.f};

    for (int qt = kc + w; qt < 32; qt += 4) {
        int q0 = qt * 64;
        #pragma unroll
        for (int qf = 0; qf < 4; qf++) {
            int row = q0 + qf*16 + l16;
            s8v a0 = *(const s8v*)(qp + (size_t)row*64 + quad*8);
            s8v a1 = *(const s8v*)(qp + (size_t)row*64 + 32 + quad*8);
            float4 linv4 = *(const float4*)(lp + q0 + qf*16 + quad*4);
            f4v acc[4];
            #pragma unroll
            for (int nt = 0; nt < 4; nt++) { acc[nt][0]=0.f; acc[nt][1]=0.f; acc[nt][2]=0.f; acc[nt][3]=0.f; }
            #pragma unroll
            for (int nt = 0; nt < 4; nt++) {
                acc[nt] = __builtin_amdgcn_mfma_f32_16x16x32_bf16(a0, bk[0][nt], acc[nt], 0, 0, 0);
                acc[nt] = __builtin_amdgcn_mfma_f32_16x16x32_bf16(a1, bk[1][nt], acc[nt], 0, 0, 0);
            }
            float lv[4] = { linv4.x, linv4.y, linv4.z, linv4.w };
            if (qt > kc) {
                #pragma unroll
                for (int nt = 0; nt < 4; nt++)
                    #pragma unroll
                    for (int reg = 0; reg < 4; reg++)
                        cs[nt] += fexp2(acc[nt][reg]) * lv[reg];
            } else {   // diagonal tile: causal predicate
                #pragma unroll
                for (int nt = 0; nt < 4; nt++) {
                    int kg = k0 + nt*16 + l16;
                    #pragma unroll
                    for (int reg = 0; reg < 4; reg++) {
                        float me = (kg <= q0 + qf*16 + quad*4 + reg) ? 1.f : 0.f;
                        cs[nt] += fexp2(acc[nt][reg]) * lv[reg] * me;
                    }
                }
            }
        }
    }

    // apply key mask, reduce over quads (row-lanes)
    #pragma unroll
    for (int nt = 0; nt < 4; nt++) {
        float v = cs[nt] * mk[nt];
        v += __shfl_xor(v, 16);
        v += __shfl_xor(v, 32);
        if (quad == 0) cred[w][nt*16 + l16] = v;
    }
    __syncthreads();
    if (tid < 64)
        atomicAdd(&imp[b*T_ + k0 + tid],
                  cred[0][tid] + cred[1][tid] + cred[2][tid] + cred[3][tid]);
}

// ---------------- mask finalize: cm, loss, survivor count ----------------
__global__ __launch_bounds__(256) void mask_finalize(
    const float* __restrict__ imp, const float* __restrict__ amask,
    const float* __restrict__ prot, const float* __restrict__ thr,
    float* __restrict__ mask_out, float* __restrict__ loss_out,
    int* __restrict__ nsurv)
{
    int i = blockIdx.x * 256 + threadIdx.x;
    float impv = imp[i] * (1.0f / (float)(H_ * T_));
    float pm = (impv >= thr[0]) ? 1.f : 0.f;
    if (prot[i] > 0.f) pm = 1.f;
    float cm = amask[i] * pm;
    mask_out[i] = cm;
    if (i == 0) loss_out[0] = 0.f;
    unsigned long long bal = __ballot(cm != 0.f);
    int cnt = __popcll(bal);
    __shared__ int bs;
    if (threadIdx.x == 0) bs = 0;
    __syncthreads();
    if ((threadIdx.x & 63) == 0 && cnt) atomicAdd(&bs, cnt);
    __syncthreads();
    if (threadIdx.x == 0 && bs) atomicAdd(nsurv, bs);
}

// ---------------- full attention (dense fallback; Q pre-scaled, exp2 domain) ----------------
__global__ __launch_bounds__(256) void attn_full(
    const unsigned short* __restrict__ qh, const unsigned short* __restrict__ kh,
    const unsigned short* __restrict__ vh, const float* __restrict__ amask,
    unsigned short* __restrict__ y, const int* __restrict__ flag)
{
    if (flag[0] == 0) return;
    __shared__ unsigned short Ks[64][72];
    __shared__ unsigned short Vt[64][72];
    __shared__ unsigned short Ps[4][16][72];
    __shared__ float mks[64];

    int tid = threadIdx.x;
    int w = tid >> 6, lane = tid & 63, quad = lane >> 4, l16 = lane & 15;
    int nqt = T_ / 64;
    int qt = blockIdx.x % nqt;
    int bh = blockIdx.x / nqt;
    int b = bh >> 4, h = bh & 15;
    int q0 = qt * 64;

    const unsigned short* qp = qh + (size_t)bh * T_ * 64;
    const unsigned short* kp = kh + (size_t)bh * T_ * 64;
    const unsigned short* vp = vh + (size_t)bh * T_ * 64;

    int qrow = q0 + 16*w + l16;
    s8v aQ0 = *(const s8v*)(qp + (size_t)qrow*64 + quad*8);
    s8v aQ1 = *(const s8v*)(qp + (size_t)qrow*64 + 32 + quad*8);

    int qwmax = q0 + 16*w + 15;
    int ntiles = qt + 1;
    int qg = q0 + 16*w + quad*4;

    float lrow[4] = {0.f, 0.f, 0.f, 0.f};
    for (int it = 0; it < ntiles; ++it) {
        int k0 = it * 64;
        __syncthreads();
        for (int cid = tid; cid < 512; cid += 256) {
            int row = cid >> 3, ch = cid & 7;
            *(s8v*)&Ks[row][ch*8] = *(const s8v*)(kp + (size_t)(k0+row)*64 + ch*8);
        }
        if (tid < 64) mks[tid] = amask[b*T_ + k0 + tid];
        __syncthreads();
        if (k0 > qwmax) continue;
        f4v accS[4];
        #pragma unroll
        for (int nt = 0; nt < 4; nt++) { accS[nt][0]=0.f; accS[nt][1]=0.f; accS[nt][2]=0.f; accS[nt][3]=0.f; }
        #pragma unroll
        for (int nt = 0; nt < 4; nt++) {
            s8v b0 = *(const s8v*)&Ks[nt*16 + l16][quad*8];
            s8v b1 = *(const s8v*)&Ks[nt*16 + l16][32 + quad*8];
            accS[nt] = __builtin_amdgcn_mfma_f32_16x16x32_bf16(aQ0, b0, accS[nt], 0, 0, 0);
            accS[nt] = __builtin_amdgcn_mfma_f32_16x16x32_bf16(aQ1, b1, accS[nt], 0, 0, 0);
        }
        #pragma unroll
        for (int nt = 0; nt < 4; nt++) {
            int kg = k0 + nt*16 + l16;
            float mkv = mks[nt*16 + l16];
            #pragma unroll
            for (int reg = 0; reg < 4; reg++) {
                bool val = (kg <= qg + reg) && (mkv != 0.f);
                float e = fexp2(accS[nt][reg]);
                lrow[reg] += val ? e : 0.f;
            }
        }
    }
    float linv[4];
    #pragma unroll
    for (int reg = 0; reg < 4; reg++) {
        float v = lrow[reg];
        v += __shfl_xor(v, 1); v += __shfl_xor(v, 2);
        v += __shfl_xor(v, 4); v += __shfl_xor(v, 8);
        linv[reg] = (v > 0.f) ? 1.0f / v : 0.f;
    }

    f4v accO[4];
    #pragma unroll
    for (int nt = 0; nt < 4; nt++) { accO[nt][0]=0.f; accO[nt][1]=0.f; accO[nt][2]=0.f; accO[nt][3]=0.f; }

    for (int it = 0; it < ntiles; ++it) {
        int k0 = it * 64;
        __syncthreads();
        for (int cid = tid; cid < 512; cid += 256) {
            int row = cid >> 3, ch = cid & 7;
            s8v kv = *(const s8v*)(kp + (size_t)(k0+row)*64 + ch*8);
            *(s8v*)&Ks[row][ch*8] = kv;
            s8v vv = *(const s8v*)(vp + (size_t)(k0+row)*64 + ch*8);
            #pragma unroll
            for (int j = 0; j < 8; j++) Vt[ch*8 + j][row] = (unsigned short)vv[j];
        }
        if (tid < 64) mks[tid] = amask[b*T_ + k0 + tid];
        __syncthreads();
        if (k0 > qwmax) continue;
        f4v accS[4];
        #pragma unroll
        for (int nt = 0; nt < 4; nt++) { accS[nt][0]=0.f; accS[nt][1]=0.f; accS[nt][2]=0.f; accS[nt][3]=0.f; }
        #pragma unroll
        for (int nt = 0; nt < 4; nt++) {
            s8v b0 = *(const s8v*)&Ks[nt*16 + l16][quad*8];
            s8v b1 = *(const s8v*)&Ks[nt*16 + l16][32 + quad*8];
            accS[nt] = __builtin_amdgcn_mfma_f32_16x16x32_bf16(aQ0, b0, accS[nt], 0, 0, 0);
            accS[nt] = __builtin_amdgcn_mfma_f32_16x16x32_bf16(aQ1, b1, accS[nt], 0, 0, 0);
        }
        #pragma unroll
        for (int nt = 0; nt < 4; nt++) {
            int kg = k0 + nt*16 + l16;
            float mkv = mks[nt*16 + l16];
            #pragma unroll
            for (int reg = 0; reg < 4; reg++) {
                bool val = (kg <= qg + reg) && (mkv != 0.f);
                float p = val ? fexp2(accS[nt][reg]) * linv[reg] : 0.f;
                Ps[w][quad*4 + reg][nt*16 + l16] = f2bf(p);
            }
        }
        s8v aP0 = *(const s8v*)&Ps[w][l16][quad*8];
        s8v aP1 = *(const s8v*)&Ps[w][l16][32 + quad*8];
        #pragma unroll
        for (int nt = 0; nt < 4; nt++) {
            s8v bv0 = *(const s8v*)&Vt[nt*16 + l16][quad*8];
            s8v bv1 = *(const s8v*)&Vt[nt*16 + l16][32 + quad*8];
            accO[nt] = __builtin_amdgcn_mfma_f32_16x16x32_bf16(aP0, bv0, accO[nt], 0, 0, 0);
            accO[nt] = __builtin_amdgcn_mfma_f32_16x16x32_bf16(aP1, bv1, accO[nt], 0, 0, 0);
        }
    }
    #pragma unroll
    for (int nt = 0; nt < 4; nt++) {
        #pragma unroll
        for (int reg = 0; reg < 4; reg++) {
            int q = q0 + 16*w + quad*4 + reg;
            y[((size_t)(b*T_ + q))*C_ + h*64 + nt*16 + l16] = f2bf(accO[nt][reg]);
        }
    }
}

// ---------------- all-pruned fast path: one-row MLP + broadcast ----------------
__global__ __launch_bounds__(256) void ap_fc(const int* __restrict__ nsurv,
        const float* __restrict__ ln2b, const float* __restrict__ fcw,
        const float* __restrict__ fcb, float* __restrict__ abuf)
{
    if (nsurv[0] != 0) return;
    int j = blockIdx.x * 4 + (threadIdx.x >> 6);
    int lane = threadIdx.x & 63;
    const float* wr = fcw + (size_t)j * C_;
    float s = 0.f;
    for (int k = lane; k < C_; k += 64) s += ln2b[k] * wr[k];
    #pragma unroll
    for (int off = 32; off > 0; off >>= 1) s += __shfl_down(s, off, 64);
    if (lane == 0) {
        float v = fcb[j] + s;
        abuf[j] = 0.5f * v * (1.0f + erff(v * 0.70710678118654752f));
    }
}

__global__ __launch_bounds__(256) void ap_fcp(const int* __restrict__ nsurv,
        const float* __restrict__ abuf, const float* __restrict__ fcpw,
        const float* __restrict__ fcpb, float* __restrict__ rowbuf)
{
    if (nsurv[0] != 0) return;
    int c = blockIdx.x * 4 + (threadIdx.x >> 6);
    int lane = threadIdx.x & 63;
    const float* wr = fcpw + (size_t)c * (4*C_);
    float s = 0.f;
    for (int k = lane; k < 4*C_; k += 64) s += abuf[k] * wr[k];
    #pragma unroll
    for (int off = 32; off > 0; off >>= 1) s += __shfl_down(s, off, 64);
    if (lane == 0) rowbuf[c] = fcpb[c] + s;
}

__global__ __launch_bounds__(256) void ap_bcast(const int* __restrict__ nsurv,
        const float* __restrict__ rowbuf, float* __restrict__ out_x)
{
    if (nsurv[0] != 0) return;
    int r = blockIdx.x;
    float4 v = ((const float4*)rowbuf)[threadIdx.x];
    ((float4*)(out_x + (size_t)r * C_))[threadIdx.x] = v;
}

extern "C" void kernel_launch(void* const* d_in, const int* in_sizes, int n_in,
                              void* d_out, int out_size, void* d_ws, size_t ws_size,
                              hipStream_t stream) {
    const float* x       = (const float*)d_in[0];
    const float* amask   = (const float*)d_in[1];
    const float* prot    = (const float*)d_in[2];
    const float* ln1w    = (const float*)d_in[3];
    const float* ln1b    = (const float*)d_in[4];
    const float* cattn_w = (const float*)d_in[5];
    const float* cattn_b = (const float*)d_in[6];
    const float* cproj_w = (const float*)d_in[7];
    const float* cproj_b = (const float*)d_in[8];
    const float* ln2w    = (const float*)d_in[9];
    const float* ln2b    = (const float*)d_in[10];
    const float* fcw     = (const float*)d_in[11];
    const float* fcb     = (const float*)d_in[12];
    const float* fcpw    = (const float*)d_in[13];
    const float* fcpb    = (const float*)d_in[14];
    const float* thr     = (const float*)d_in[15];

    unsigned short* wqkv  = (unsigned short*)d_ws;
    unsigned short* wproj = wqkv  + (size_t)3*C_*C_;
    unsigned short* wfc   = wproj + (size_t)C_*C_;
    unsigned short* wfcp  = wfc   + (size_t)4*C_*C_;
    unsigned short* hbuf  = wfcp  + (size_t)4*C_*C_;
    unsigned short* qh    = hbuf  + (size_t)NROWS*C_;
    unsigned short* kh    = qh    + (size_t)NROWS*C_;
    unsigned short* vh    = kh    + (size_t)NROWS*C_;
    unsigned short* cbuf  = qh;                        // fc chunk out (dense path)
    float* imp    = (float*)(vh + (size_t)NROWS*C_);
    int*   nsurv  = (int*)(imp + NROWS);
    float* abuf   = (float*)(nsurv + 4);
    float* rowbuf = abuf + 4*C_;
    float* linvbuf = rowbuf + C_;                      // 64*2048 fp32

    float* out_x    = (float*)d_out;
    float* out_mask = out_x + (size_t)NROWS*C_;
    float* out_loss = out_mask + NROWS;

    hipLaunchKernelGGL(zero_kernel, dim3((NROWS+8+255)/256), dim3(256), 0, stream,
                       imp, NROWS + 4);
    hipLaunchKernelGGL(cvt_bf16, dim3(3*C_*C_/4/256), dim3(256), 0, stream,
                       cattn_w, wqkv, 3*C_*C_/4, nullptr);
    hipLaunchKernelGGL(ln_bf16, dim3(NROWS), dim3(256), 0, stream, x, ln1w, ln1b, hbuf, nullptr);
    // QK GEMM (N = 2048) -> qh/kh head-major (q pre-scaled by QSCALE)
    hipLaunchKernelGGL((gemm_bf16<3>), dim3(2048/128, NROWS/128), dim3(256), 0, stream,
                       hbuf, wqkv, cattn_b, nullptr, nullptr, nullptr,
                       C_, C_, C_, 0, 0, nullptr, qh, kh, vh, nullptr);
    // attention: two barrier-free streaming passes
    hipLaunchKernelGGL(attn_rowsum, dim3(64*32), dim3(256), 0, stream,
                       qh, kh, amask, linvbuf);
    hipLaunchKernelGGL(attn_colsum, dim3(64*32), dim3(256), 0, stream,
                       qh, kh, amask, linvbuf, imp);
    hipLaunchKernelGGL(mask_finalize, dim3(NROWS/256), dim3(256), 0, stream,
                       imp, amask, prot, thr, out_mask, out_loss, nsurv);

    // ---- dense fallback path (early-exit when nsurv == 0) ----
    hipLaunchKernelGGL(cvt3_bf16, dim3(9*C_*C_/4/256), dim3(256), 0, stream,
                       cproj_w, fcw, fcpw, wproj, wfc, wfcp, nsurv);
    hipLaunchKernelGGL((gemm_bf16<3>), dim3(1024/128, NROWS/128), dim3(256), 0, stream,
                       hbuf, wqkv + (size_t)2048*C_, cattn_b + 2048, nullptr, nullptr, nullptr,
                       C_, C_, C_, 0, 2048, nullptr, qh, kh, vh, nsurv);
    hipLaunchKernelGGL(attn_full, dim3(B_*H_*(T_/64)), dim3(256), 0, stream,
                       qh, kh, vh, amask, hbuf, nsurv);
    hipLaunchKernelGGL((gemm_bf16<4>), dim3(C_/128, NROWS/128), dim3(256), 0, stream,
                       hbuf, wproj, cproj_b, x, out_x, nullptr,
                       C_, C_, C_, C_, 0, out_mask, nullptr, nullptr, nullptr, nsurv);
    hipLaunchKernelGGL(ln_bf16, dim3(NROWS), dim3(256), 0, stream, out_x, ln2w, ln2b, hbuf, nsurv);
    for (int j = 0; j < 2; j++) {
        hipLaunchKernelGGL((gemm_bf16<1>), dim3(2048/128, NROWS/128), dim3(256), 0, stream,
                           hbuf, wfc + (size_t)j*2048*C_, fcb + j*2048, nullptr, nullptr, cbuf,
                           C_, C_, C_, 2048, 0, nullptr, nullptr, nullptr, nullptr, nsurv);
        hipLaunchKernelGGL((gemm_bf16<2>), dim3(C_/128, NROWS/128), dim3(256), 0, stream,
                           cbuf, wfcp + (size_t)j*2048, (j == 0) ? fcpb : nullptr, out_x, out_x, nullptr,
                           2048, 2048, 4*C_, C_, 0, nullptr, nullptr, nullptr, nullptr, nsurv);
    }

    // ---- all-pruned fast path (early-exit when nsurv != 0) ----
    hipLaunchKernelGGL(ap_fc,    dim3(4*C_/4), dim3(256), 0, stream, nsurv, ln2b, fcw, fcb, abuf);
    hipLaunchKernelGGL(ap_fcp,   dim3(C_/4),   dim3(256), 0, stream, nsurv, abuf, fcpw, fcpb, rowbuf);
    hipLaunchKernelGGL(ap_bcast, dim3(NROWS),  dim3(256), 0, stream, nsurv, rowbuf, out_x);
}

// Round 9
// 311.426 us; speedup vs baseline: 1.2937x; 1.1180x over previous
//
#include <hip/hip_runtime.h>
#include <math.h>

#define B_ 4
#define T_ 2048
#define C_ 1024
#define H_ 16
#define NROWS (B_*T_)   // 8192

typedef short s8v  __attribute__((ext_vector_type(8)));
typedef float f4v  __attribute__((ext_vector_type(4)));
typedef unsigned short u16v4 __attribute__((ext_vector_type(4)));

#define QSCALE 0.1803368801111f   // 0.125 * log2(e): scores in log2 domain

static __device__ __forceinline__ unsigned short f2bf(float x) {
    unsigned u = __float_as_uint(x);
    unsigned r = u + 0x7fffu + ((u >> 16) & 1u);
    return (unsigned short)(r >> 16);
}

static __device__ __forceinline__ float fexp2(float x) {
    return __builtin_amdgcn_exp2f(x);
}

static __device__ __forceinline__ void gload_lds16(const void* g, void* l) {
    __builtin_amdgcn_global_load_lds(
        (const __attribute__((address_space(1))) void*)g,
        (__attribute__((address_space(3))) void*)l, 16, 0, 0);
}

// ---- prep: LN1 row + qkv-weight cvt slice + zero imp/nsurv (grid NROWS) ----
__global__ __launch_bounds__(256) void prep_kernel(
        const float* __restrict__ x, const float* __restrict__ w,
        const float* __restrict__ b, unsigned short* __restrict__ out,
        const float* __restrict__ wsrc, unsigned short* __restrict__ wdst,
        float* __restrict__ imp, int* __restrict__ nsurv)
{
    int row = blockIdx.x;
    int tid = threadIdx.x;
    // qkv weight convert slice: 8192 blocks x 96 vec4 = 786432 = 3C*C/4
    int widx = row * 96 + tid;
    if (tid < 96) {
        float4 v = ((const float4*)wsrc)[widx];
        u16v4 o = { f2bf(v.x), f2bf(v.y), f2bf(v.z), f2bf(v.w) };
        *(u16v4*)(wdst + (size_t)widx*4) = o;
    }
    if (row < 32) imp[row*256 + tid] = 0.f;
    if (row == 32 && tid < 8) nsurv[tid] = 0;

    const float4* xr = (const float4*)(x + (size_t)row * C_);
    float4 v = xr[tid];
    float s  = v.x + v.y + v.z + v.w;
    float ss = v.x*v.x + v.y*v.y + v.z*v.z + v.w*v.w;
    #pragma unroll
    for (int off = 32; off > 0; off >>= 1) {
        s  += __shfl_down(s,  off, 64);
        ss += __shfl_down(ss, off, 64);
    }
    __shared__ float rs[4], rss[4];
    __shared__ float smu, srstd;
    int wave = tid >> 6, lane = tid & 63;
    if (lane == 0) { rs[wave] = s; rss[wave] = ss; }
    __syncthreads();
    if (tid == 0) {
        float S  = rs[0]+rs[1]+rs[2]+rs[3];
        float SS = rss[0]+rss[1]+rss[2]+rss[3];
        float mu = S * (1.0f/C_);
        float var = SS * (1.0f/C_) - mu*mu;
        smu = mu; srstd = rsqrtf(var + 1e-5f);
    }
    __syncthreads();
    float mu = smu, rstd = srstd;
    float4 wv = ((const float4*)w)[tid];
    float4 bv = ((const float4*)b)[tid];
    u16v4 o;
    o.x = f2bf((v.x-mu)*rstd*wv.x + bv.x);
    o.y = f2bf((v.y-mu)*rstd*wv.y + bv.y);
    o.z = f2bf((v.z-mu)*rstd*wv.z + bv.z);
    o.w = f2bf((v.w-mu)*rstd*wv.w + bv.w);
    *(u16v4*)(out + (size_t)row * C_ + tid*4) = o;
}

// ---- LayerNorm -> bf16 (flagged, persistent over nrows) ----
__global__ __launch_bounds__(256) void ln_bf16(const float* __restrict__ x,
        const float* __restrict__ w, const float* __restrict__ b,
        unsigned short* __restrict__ out, const int* __restrict__ flag, int nrows)
{
    if (flag && flag[0] == 0) return;
    int tid = threadIdx.x;
    __shared__ float rs[4], rss[4];
    __shared__ float smu, srstd;
    int wave = tid >> 6, lane = tid & 63;
    for (int row = blockIdx.x; row < nrows; row += gridDim.x) {
        const float4* xr = (const float4*)(x + (size_t)row * C_);
        float4 v = xr[tid];
        float s  = v.x + v.y + v.z + v.w;
        float ss = v.x*v.x + v.y*v.y + v.z*v.z + v.w*v.w;
        #pragma unroll
        for (int off = 32; off > 0; off >>= 1) {
            s  += __shfl_down(s,  off, 64);
            ss += __shfl_down(ss, off, 64);
        }
        if (lane == 0) { rs[wave] = s; rss[wave] = ss; }
        __syncthreads();
        if (tid == 0) {
            float S  = rs[0]+rs[1]+rs[2]+rs[3];
            float SS = rss[0]+rss[1]+rss[2]+rss[3];
            float mu = S * (1.0f/C_);
            float var = SS * (1.0f/C_) - mu*mu;
            smu = mu; srstd = rsqrtf(var + 1e-5f);
        }
        __syncthreads();
        float mu = smu, rstd = srstd;
        float4 wv = ((const float4*)w)[tid];
        float4 bv = ((const float4*)b)[tid];
        u16v4 o;
        o.x = f2bf((v.x-mu)*rstd*wv.x + bv.x);
        o.y = f2bf((v.y-mu)*rstd*wv.y + bv.y);
        o.z = f2bf((v.z-mu)*rstd*wv.z + bv.z);
        o.w = f2bf((v.w-mu)*rstd*wv.w + bv.w);
        *(u16v4*)(out + (size_t)row * C_ + tid*4) = o;
        __syncthreads();
    }
}

// ---- merged flagged cvt of cproj/fc/fcproj weights (persistent) ----
__global__ __launch_bounds__(256) void cvt3_bf16(
        const float* __restrict__ cprojw, const float* __restrict__ fcw,
        const float* __restrict__ fcpw,
        unsigned short* __restrict__ wproj, unsigned short* __restrict__ wfc,
        unsigned short* __restrict__ wfcp, const int* __restrict__ flag)
{
    if (flag[0] == 0) return;
    const int total = 9*C_*C_/4;
    const int n1 = C_*C_/4;
    const int n2 = n1 + C_*C_;
    for (int i = blockIdx.x * 256 + threadIdx.x; i < total; i += gridDim.x * 256) {
        const float* src; unsigned short* dst; int j;
        if (i < n1)      { src = cprojw; dst = wproj; j = i; }
        else if (i < n2) { src = fcw;    dst = wfc;   j = i - n1; }
        else             { src = fcpw;   dst = wfcp;  j = i - n2; }
        float4 v = ((const float4*)src)[j];
        u16v4 o = { f2bf(v.x), f2bf(v.y), f2bf(v.z), f2bf(v.w) };
        *(u16v4*)(dst + (size_t)j*4) = o;
    }
}

// ---------------- bf16 MFMA GEMM (persistent virtual-block loop) ----------------
// EPI: 1 = bias + exact GELU -> bf16 ; 2 = bias(opt) + fp32 residual -> fp32
//      3 = bias -> bf16 head-major qkv scatter (q pre-scaled by QSCALE)
//      4 = bias + (res + v)*cm -> fp32
template<int EPI>
__global__ __launch_bounds__(256) void gemm_bf16(
    const unsigned short* __restrict__ A,
    const unsigned short* __restrict__ Bw,
    const float* __restrict__ bias,
    const float* __restrict__ res,
    float* __restrict__ Cout, unsigned short* __restrict__ Cbf,
    int K, int lda, int ldb, int ldc, int ncoff,
    const float* __restrict__ cmv,
    unsigned short* __restrict__ qh, unsigned short* __restrict__ kh,
    unsigned short* __restrict__ vh, const int* __restrict__ flag,
    int nbx, int nby)
{
    if (flag && flag[0] == 0) return;
    __shared__ unsigned short As[128*64];
    __shared__ unsigned short Bs[128*64];
    int tid = threadIdx.x;
    int w = tid >> 6, lane = tid & 63, quad = lane >> 4, l16 = lane & 15;
    int wr = w >> 1, wc = w & 1;

    int nvb = nbx * nby;
    int vb0 = blockIdx.y * gridDim.x + blockIdx.x;
    int vstride = gridDim.x * gridDim.y;

    for (int vb = vb0; vb < nvb; vb += vstride) {
        int n0 = (vb % nbx) * 128;
        int m0 = (vb / nbx) * 128;

        size_t offA[4], offB[4];
        #pragma unroll
        for (int j = 0; j < 4; j++) {
            int ci = j*256 + tid;
            int mr = ci >> 3, kcs = ci & 7;
            int kc = kcs ^ (mr & 7);
            offA[j] = (size_t)(m0 + mr) * lda + kc*8;
            offB[j] = (size_t)(n0 + mr) * ldb + kc*8;
        }

        f4v acc[4][4];
        #pragma unroll
        for (int i = 0; i < 4; i++)
            #pragma unroll
            for (int j = 0; j < 4; j++) { acc[i][j][0]=0.f; acc[i][j][1]=0.f; acc[i][j][2]=0.f; acc[i][j][3]=0.f; }

        for (int k0 = 0; k0 < K; k0 += 64) {
            __syncthreads();
            #pragma unroll
            for (int j = 0; j < 4; j++) {
                gload_lds16(A  + offA[j] + k0, &As[(j*256 + (w<<6))*8]);
                gload_lds16(Bw + offB[j] + k0, &Bs[(j*256 + (w<<6))*8]);
            }
            __syncthreads();
            #pragma unroll
            for (int c = 0; c < 2; c++) {
                s8v af[4], bf[4];
                int sw = ((c<<2) + quad) ^ (l16 & 7);
                #pragma unroll
                for (int i = 0; i < 4; i++) {
                    int mr = wr*64 + i*16 + l16;
                    af[i] = *(const s8v*)&As[mr*64 + sw*8];
                    int nr = wc*64 + i*16 + l16;
                    bf[i] = *(const s8v*)&Bs[nr*64 + sw*8];
                }
                #pragma unroll
                for (int i = 0; i < 4; i++)
                    #pragma unroll
                    for (int j = 0; j < 4; j++)
                        acc[i][j] = __builtin_amdgcn_mfma_f32_16x16x32_bf16(af[i], bf[j], acc[i][j], 0, 0, 0);
            }
        }

        #pragma unroll
        for (int j = 0; j < 4; j++) {
            int ncol = n0 + wc*64 + j*16 + l16;
            float bv = bias ? bias[ncol] : 0.f;
            int hh = 0, dd = 0;
            bool qsec = false;
            unsigned short* basep = nullptr;
            if (EPI == 3) {
                int ncolg = ncol + ncoff;
                int sec = ncolg >> 10;
                int hn = ncolg & 1023;
                hh = hn >> 6; dd = hn & 63;
                basep = (sec == 0) ? qh : (sec == 1) ? kh : vh;
                qsec = (sec == 0);
            }
            #pragma unroll
            for (int i = 0; i < 4; i++) {
                #pragma unroll
                for (int reg = 0; reg < 4; reg++) {
                    int m = m0 + wr*64 + i*16 + quad*4 + reg;
                    float v = acc[i][j][reg] + bv;
                    if (EPI == 1) {
                        v = 0.5f * v * (1.0f + erff(v * 0.70710678118654752f));
                        Cbf[(size_t)m*ldc + ncol] = f2bf(v);
                    } else if (EPI == 2) {
                        Cout[(size_t)m*ldc + ncol] = v + res[(size_t)m*ldc + ncol];
                    } else if (EPI == 3) {
                        if (qsec) v *= QSCALE;
                        int bb = m >> 11, t = m & 2047;
                        basep[(((size_t)(bb*H_ + hh))*T_ + t)*64 + dd] = f2bf(v);
                    } else if (EPI == 4) {
                        Cout[(size_t)m*ldc + ncol] = (res[(size_t)m*ldc + ncol] + v) * cmv[m];
                    }
                }
            }
        }
    }
}

// ---------------- attention pass 1: linv[bh][q] = 1/sum_k exp2(s) ----------------
__global__ __launch_bounds__(256) void attn_rowsum(
    const unsigned short* __restrict__ qh, const unsigned short* __restrict__ kh,
    const float* __restrict__ amask, float* __restrict__ linvbuf)
{
    __shared__ float msk01[2048];
    __shared__ float lred[4][64];

    int tid = threadIdx.x;
    int w = tid >> 6, lane = tid & 63, quad = lane >> 4, l16 = lane & 15;
    int qt = 31 - (blockIdx.x >> 6);     // heavy blocks first
    int bh = blockIdx.x & 63;
    int b  = bh >> 4;
    int q0 = qt * 64;
    int ntiles = qt + 1;

    const unsigned short* qp = qh + (size_t)bh*T_*64;
    const unsigned short* kp = kh + (size_t)bh*T_*64;
    const float* amp = amask + b*T_;

    for (int i = tid; i < ntiles*64; i += 256)
        msk01[i] = (amp[i] != 0.f) ? 1.f : 0.f;
    __syncthreads();

    s8v aQ[4][2];
    #pragma unroll
    for (int qf = 0; qf < 4; qf++) {
        int row = q0 + qf*16 + l16;
        aQ[qf][0] = *(const s8v*)(qp + (size_t)row*64 + quad*8);
        aQ[qf][1] = *(const s8v*)(qp + (size_t)row*64 + 32 + quad*8);
    }

    float lrow[4][4];
    #pragma unroll
    for (int qf = 0; qf < 4; qf++)
        #pragma unroll
        for (int reg = 0; reg < 4; reg++) lrow[qf][reg] = 0.f;

    for (int it = w; it < ntiles; it += 4) {
        int k0 = it * 64;
        s8v bk[2][4];
        #pragma unroll
        for (int c = 0; c < 2; c++)
            #pragma unroll
            for (int nt = 0; nt < 4; nt++)
                bk[c][nt] = *(const s8v*)(kp + (size_t)(k0 + nt*16 + l16)*64 + c*32 + quad*8);
        float mk[4];
        #pragma unroll
        for (int nt = 0; nt < 4; nt++) mk[nt] = msk01[k0 + nt*16 + l16];
        bool allm = __all(mk[0] != 0.f && mk[1] != 0.f && mk[2] != 0.f && mk[3] != 0.f);

        #pragma unroll
        for (int qf = 0; qf < 4; qf++) {
            f4v acc[4];
            #pragma unroll
            for (int nt = 0; nt < 4; nt++) { acc[nt][0]=0.f; acc[nt][1]=0.f; acc[nt][2]=0.f; acc[nt][3]=0.f; }
            #pragma unroll
            for (int c = 0; c < 2; c++)
                #pragma unroll
                for (int nt = 0; nt < 4; nt++)
                    acc[nt] = __builtin_amdgcn_mfma_f32_16x16x32_bf16(aQ[qf][c], bk[c][nt], acc[nt], 0, 0, 0);
            if (it < qt && allm) {
                #pragma unroll
                for (int nt = 0; nt < 4; nt++)
                    #pragma unroll
                    for (int reg = 0; reg < 4; reg++)
                        lrow[qf][reg] += fexp2(acc[nt][reg]);
            } else if (it < qt) {
                #pragma unroll
                for (int nt = 0; nt < 4; nt++)
                    #pragma unroll
                    for (int reg = 0; reg < 4; reg++)
                        lrow[qf][reg] += fexp2(acc[nt][reg]) * mk[nt];
            } else {
                #pragma unroll
                for (int nt = 0; nt < 4; nt++) {
                    int kg = k0 + nt*16 + l16;
                    #pragma unroll
                    for (int reg = 0; reg < 4; reg++) {
                        float me = (kg <= q0 + qf*16 + quad*4 + reg) ? mk[nt] : 0.f;
                        lrow[qf][reg] += fexp2(acc[nt][reg]) * me;
                    }
                }
            }
        }
    }

    #pragma unroll
    for (int qf = 0; qf < 4; qf++)
        #pragma unroll
        for (int reg = 0; reg < 4; reg++) {
            float v = lrow[qf][reg];
            v += __shfl_xor(v, 1); v += __shfl_xor(v, 2);
            v += __shfl_xor(v, 4); v += __shfl_xor(v, 8);
            lrow[qf][reg] = v;
        }
    if (l16 == 0) {
        #pragma unroll
        for (int qf = 0; qf < 4; qf++)
            #pragma unroll
            for (int reg = 0; reg < 4; reg++)
                lred[w][qf*16 + quad*4 + reg] = lrow[qf][reg];
    }
    __syncthreads();
    if (tid < 64) {
        float t = lred[0][tid] + lred[1][tid] + lred[2][tid] + lred[3][tid];
        linvbuf[(size_t)bh*T_ + q0 + tid] = (t > 0.f) ? 1.0f / t : 0.f;
    }
}

// ---------------- attention pass 2: imp[b][k] += sum_{h,q} exp2(s)*linv ----------------
__global__ __launch_bounds__(256) void attn_colsum(
    const unsigned short* __restrict__ qh, const unsigned short* __restrict__ kh,
    const float* __restrict__ amask, const float* __restrict__ linvbuf,
    float* __restrict__ imp)
{
    __shared__ float cred[4][64];

    int tid = threadIdx.x;
    int w = tid >> 6, lane = tid & 63, quad = lane >> 4, l16 = lane & 15;
    int kc = blockIdx.x >> 6;
    int bh = blockIdx.x & 63;
    int b  = bh >> 4;
    int k0 = kc * 64;

    const unsigned short* qp = qh + (size_t)bh*T_*64;
    const unsigned short* kp = kh + (size_t)bh*T_*64;
    const float* lp = linvbuf + (size_t)bh*T_;

    s8v bk[2][4];
    float mk[4];
    #pragma unroll
    for (int nt = 0; nt < 4; nt++) {
        int key = k0 + nt*16 + l16;
        bk[0][nt] = *(const s8v*)(kp + (size_t)key*64 + quad*8);
        bk[1][nt] = *(const s8v*)(kp + (size_t)key*64 + 32 + quad*8);
        mk[nt] = amask[b*T_ + key];
    }

    float cs[4] = {0.f, 0.f, 0.f, 0.f};

    for (int qt = kc + w; qt < 32; qt += 4) {
        int q0 = qt * 64;
        #pragma unroll
        for (int qf = 0; qf < 4; qf++) {
            int row = q0 + qf*16 + l16;
            s8v a0 = *(const s8v*)(qp + (size_t)row*64 + quad*8);
            s8v a1 = *(const s8v*)(qp + (size_t)row*64 + 32 + quad*8);
            float4 linv4 = *(const float4*)(lp + q0 + qf*16 + quad*4);
            f4v acc[4];
            #pragma unroll
            for (int nt = 0; nt < 4; nt++) { acc[nt][0]=0.f; acc[nt][1]=0.f; acc[nt][2]=0.f; acc[nt][3]=0.f; }
            #pragma unroll
            for (int nt = 0; nt < 4; nt++) {
                acc[nt] = __builtin_amdgcn_mfma_f32_16x16x32_bf16(a0, bk[0][nt], acc[nt], 0, 0, 0);
                acc[nt] = __builtin_amdgcn_mfma_f32_16x16x32_bf16(a1, bk[1][nt], acc[nt], 0, 0, 0);
            }
            float lv[4] = { linv4.x, linv4.y, linv4.z, linv4.w };
            if (qt > kc) {
                #pragma unroll
                for (int nt = 0; nt < 4; nt++)
                    #pragma unroll
                    for (int reg = 0; reg < 4; reg++)
                        cs[nt] += fexp2(acc[nt][reg]) * lv[reg];
            } else {
                #pragma unroll
                for (int nt = 0; nt < 4; nt++) {
                    int kg = k0 + nt*16 + l16;
                    #pragma unroll
                    for (int reg = 0; reg < 4; reg++) {
                        float me = (kg <= q0 + qf*16 + quad*4 + reg) ? 1.f : 0.f;
                        cs[nt] += fexp2(acc[nt][reg]) * lv[reg] * me;
                    }
                }
            }
        }
    }

    #pragma unroll
    for (int nt = 0; nt < 4; nt++) {
        float v = cs[nt] * mk[nt];
        v += __shfl_xor(v, 16);
        v += __shfl_xor(v, 32);
        if (quad == 0) cred[w][nt*16 + l16] = v;
    }
    __syncthreads();
    if (tid < 64)
        atomicAdd(&imp[b*T_ + k0 + tid],
                  cred[0][tid] + cred[1][tid] + cred[2][tid] + cred[3][tid]);
}

// ---------------- mask finalize: cm, loss, survivor count ----------------
__global__ __launch_bounds__(256) void mask_finalize(
    const float* __restrict__ imp, const float* __restrict__ amask,
    const float* __restrict__ prot, const float* __restrict__ thr,
    float* __restrict__ mask_out, float* __restrict__ loss_out,
    int* __restrict__ nsurv)
{
    int i = blockIdx.x * 256 + threadIdx.x;
    float impv = imp[i] * (1.0f / (float)(H_ * T_));
    float pm = (impv >= thr[0]) ? 1.f : 0.f;
    if (prot[i] > 0.f) pm = 1.f;
    float cm = amask[i] * pm;
    mask_out[i] = cm;
    if (i == 0) loss_out[0] = 0.f;
    unsigned long long bal = __ballot(cm != 0.f);
    int cnt = __popcll(bal);
    __shared__ int bs;
    if (threadIdx.x == 0) bs = 0;
    __syncthreads();
    if ((threadIdx.x & 63) == 0 && cnt) atomicAdd(&bs, cnt);
    __syncthreads();
    if (threadIdx.x == 0 && bs) atomicAdd(nsurv, bs);
}

// ---------------- full attention (dense fallback; persistent) ----------------
__global__ __launch_bounds__(256) void attn_full(
    const unsigned short* __restrict__ qh, const unsigned short* __restrict__ kh,
    const unsigned short* __restrict__ vh, const float* __restrict__ amask,
    unsigned short* __restrict__ y, const int* __restrict__ flag)
{
    if (flag[0] == 0) return;
    __shared__ unsigned short Ks[64][72];
    __shared__ unsigned short Vt[64][72];
    __shared__ unsigned short Ps[4][16][72];
    __shared__ float mks[64];

    int tid = threadIdx.x;
    int w = tid >> 6, lane = tid & 63, quad = lane >> 4, l16 = lane & 15;
    int nqt = T_ / 64;

    for (int vb = blockIdx.x; vb < B_*H_*nqt; vb += gridDim.x) {
        int qt = vb % nqt;
        int bh = vb / nqt;
        int b = bh >> 4, h = bh & 15;
        int q0 = qt * 64;

        const unsigned short* qp = qh + (size_t)bh * T_ * 64;
        const unsigned short* kp = kh + (size_t)bh * T_ * 64;
        const unsigned short* vp = vh + (size_t)bh * T_ * 64;

        int qrow = q0 + 16*w + l16;
        s8v aQ0 = *(const s8v*)(qp + (size_t)qrow*64 + quad*8);
        s8v aQ1 = *(const s8v*)(qp + (size_t)qrow*64 + 32 + quad*8);

        int qwmax = q0 + 16*w + 15;
        int ntiles = qt + 1;
        int qg = q0 + 16*w + quad*4;

        float lrow[4] = {0.f, 0.f, 0.f, 0.f};
        for (int it = 0; it < ntiles; ++it) {
            int k0 = it * 64;
            __syncthreads();
            for (int cid = tid; cid < 512; cid += 256) {
                int row = cid >> 3, ch = cid & 7;
                *(s8v*)&Ks[row][ch*8] = *(const s8v*)(kp + (size_t)(k0+row)*64 + ch*8);
            }
            if (tid < 64) mks[tid] = amask[b*T_ + k0 + tid];
            __syncthreads();
            if (k0 > qwmax) continue;
            f4v accS[4];
            #pragma unroll
            for (int nt = 0; nt < 4; nt++) { accS[nt][0]=0.f; accS[nt][1]=0.f; accS[nt][2]=0.f; accS[nt][3]=0.f; }
            #pragma unroll
            for (int nt = 0; nt < 4; nt++) {
                s8v b0 = *(const s8v*)&Ks[nt*16 + l16][quad*8];
                s8v b1 = *(const s8v*)&Ks[nt*16 + l16][32 + quad*8];
                accS[nt] = __builtin_amdgcn_mfma_f32_16x16x32_bf16(aQ0, b0, accS[nt], 0, 0, 0);
                accS[nt] = __builtin_amdgcn_mfma_f32_16x16x32_bf16(aQ1, b1, accS[nt], 0, 0, 0);
            }
            #pragma unroll
            for (int nt = 0; nt < 4; nt++) {
                int kg = k0 + nt*16 + l16;
                float mkv = mks[nt*16 + l16];
                #pragma unroll
                for (int reg = 0; reg < 4; reg++) {
                    bool val = (kg <= qg + reg) && (mkv != 0.f);
                    float e = fexp2(accS[nt][reg]);
                    lrow[reg] += val ? e : 0.f;
                }
            }
        }
        float linv[4];
        #pragma unroll
        for (int reg = 0; reg < 4; reg++) {
            float v = lrow[reg];
            v += __shfl_xor(v, 1); v += __shfl_xor(v, 2);
            v += __shfl_xor(v, 4); v += __shfl_xor(v, 8);
            linv[reg] = (v > 0.f) ? 1.0f / v : 0.f;
        }

        f4v accO[4];
        #pragma unroll
        for (int nt = 0; nt < 4; nt++) { accO[nt][0]=0.f; accO[nt][1]=0.f; accO[nt][2]=0.f; accO[nt][3]=0.f; }

        for (int it = 0; it < ntiles; ++it) {
            int k0 = it * 64;
            __syncthreads();
            for (int cid = tid; cid < 512; cid += 256) {
                int row = cid >> 3, ch = cid & 7;
                s8v kv = *(const s8v*)(kp + (size_t)(k0+row)*64 + ch*8);
                *(s8v*)&Ks[row][ch*8] = kv;
                s8v vv = *(const s8v*)(vp + (size_t)(k0+row)*64 + ch*8);
                #pragma unroll
                for (int j = 0; j < 8; j++) Vt[ch*8 + j][row] = (unsigned short)vv[j];
            }
            if (tid < 64) mks[tid] = amask[b*T_ + k0 + tid];
            __syncthreads();
            if (k0 > qwmax) continue;
            f4v accS[4];
            #pragma unroll
            for (int nt = 0; nt < 4; nt++) { accS[nt][0]=0.f; accS[nt][1]=0.f; accS[nt][2]=0.f; accS[nt][3]=0.f; }
            #pragma unroll
            for (int nt = 0; nt < 4; nt++) {
                s8v b0 = *(const s8v*)&Ks[nt*16 + l16][quad*8];
                s8v b1 = *(const s8v*)&Ks[nt*16 + l16][32 + quad*8];
                accS[nt] = __builtin_amdgcn_mfma_f32_16x16x32_bf16(aQ0, b0, accS[nt], 0, 0, 0);
                accS[nt] = __builtin_amdgcn_mfma_f32_16x16x32_bf16(aQ1, b1, accS[nt], 0, 0, 0);
            }
            #pragma unroll
            for (int nt = 0; nt < 4; nt++) {
                int kg = k0 + nt*16 + l16;
                float mkv = mks[nt*16 + l16];
                #pragma unroll
                for (int reg = 0; reg < 4; reg++) {
                    bool val = (kg <= qg + reg) && (mkv != 0.f);
                    float p = val ? fexp2(accS[nt][reg]) * linv[reg] : 0.f;
                    Ps[w][quad*4 + reg][nt*16 + l16] = f2bf(p);
                }
            }
            s8v aP0 = *(const s8v*)&Ps[w][l16][quad*8];
            s8v aP1 = *(const s8v*)&Ps[w][l16][32 + quad*8];
            #pragma unroll
            for (int nt = 0; nt < 4; nt++) {
                s8v bv0 = *(const s8v*)&Vt[nt*16 + l16][quad*8];
                s8v bv1 = *(const s8v*)&Vt[nt*16 + l16][32 + quad*8];
                accO[nt] = __builtin_amdgcn_mfma_f32_16x16x32_bf16(aP0, bv0, accO[nt], 0, 0, 0);
                accO[nt] = __builtin_amdgcn_mfma_f32_16x16x32_bf16(aP1, bv1, accO[nt], 0, 0, 0);
            }
        }
        #pragma unroll
        for (int nt = 0; nt < 4; nt++) {
            #pragma unroll
            for (int reg = 0; reg < 4; reg++) {
                int q = q0 + 16*w + quad*4 + reg;
                y[((size_t)(b*T_ + q))*C_ + h*64 + nt*16 + l16] = f2bf(accO[nt][reg]);
            }
        }
        __syncthreads();
    }
}

// ---------------- all-pruned fast path: one-row MLP + broadcast ----------------
__global__ __launch_bounds__(256) void ap_fc(const int* __restrict__ nsurv,
        const float* __restrict__ ln2b, const float* __restrict__ fcw,
        const float* __restrict__ fcb, float* __restrict__ abuf)
{
    if (nsurv[0] != 0) return;
    int j = blockIdx.x * 4 + (threadIdx.x >> 6);
    int lane = threadIdx.x & 63;
    const float4* wr = (const float4*)(fcw + (size_t)j * C_);
    const float4* bb = (const float4*)ln2b;
    float s = 0.f;
    #pragma unroll
    for (int k = 0; k < 4; k++) {
        float4 a = bb[lane + 64*k];
        float4 wv = wr[lane + 64*k];
        s += a.x*wv.x + a.y*wv.y + a.z*wv.z + a.w*wv.w;
    }
    #pragma unroll
    for (int off = 32; off > 0; off >>= 1) s += __shfl_down(s, off, 64);
    if (lane == 0) {
        float v = fcb[j] + s;
        abuf[j] = 0.5f * v * (1.0f + erff(v * 0.70710678118654752f));
    }
}

__global__ __launch_bounds__(256) void ap_fcp(const int* __restrict__ nsurv,
        const float* __restrict__ abuf, const float* __restrict__ fcpw,
        const float* __restrict__ fcpb, float* __restrict__ rowbuf)
{
    if (nsurv[0] != 0) return;
    int c = blockIdx.x * 4 + (threadIdx.x >> 6);
    int lane = threadIdx.x & 63;
    const float4* wr = (const float4*)(fcpw + (size_t)c * (4*C_));
    const float4* ab = (const float4*)abuf;
    float s = 0.f;
    #pragma unroll
    for (int k = 0; k < 16; k++) {
        float4 a = ab[lane + 64*k];
        float4 wv = wr[lane + 64*k];
        s += a.x*wv.x + a.y*wv.y + a.z*wv.z + a.w*wv.w;
    }
    #pragma unroll
    for (int off = 32; off > 0; off >>= 1) s += __shfl_down(s, off, 64);
    if (lane == 0) rowbuf[c] = fcpb[c] + s;
}

__global__ __launch_bounds__(256) void ap_bcast(const int* __restrict__ nsurv,
        const float* __restrict__ rowbuf, float* __restrict__ out_x)
{
    if (nsurv[0] != 0) return;
    float4 v = ((const float4*)rowbuf)[threadIdx.x];
    for (int r = blockIdx.x; r < NROWS; r += gridDim.x)
        ((float4*)(out_x + (size_t)r * C_))[threadIdx.x] = v;
}

extern "C" void kernel_launch(void* const* d_in, const int* in_sizes, int n_in,
                              void* d_out, int out_size, void* d_ws, size_t ws_size,
                              hipStream_t stream) {
    const float* x       = (const float*)d_in[0];
    const float* amask   = (const float*)d_in[1];
    const float* prot    = (const float*)d_in[2];
    const float* ln1w    = (const float*)d_in[3];
    const float* ln1b    = (const float*)d_in[4];
    const float* cattn_w = (const float*)d_in[5];
    const float* cattn_b = (const float*)d_in[6];
    const float* cproj_w = (const float*)d_in[7];
    const float* cproj_b = (const float*)d_in[8];
    const float* ln2w    = (const float*)d_in[9];
    const float* ln2b    = (const float*)d_in[10];
    const float* fcw     = (const float*)d_in[11];
    const float* fcb     = (const float*)d_in[12];
    const float* fcpw    = (const float*)d_in[13];
    const float* fcpb    = (const float*)d_in[14];
    const float* thr     = (const float*)d_in[15];

    unsigned short* wqkv  = (unsigned short*)d_ws;
    unsigned short* wproj = wqkv  + (size_t)3*C_*C_;
    unsigned short* wfc   = wproj + (size_t)C_*C_;
    unsigned short* wfcp  = wfc   + (size_t)4*C_*C_;
    unsigned short* hbuf  = wfcp  + (size_t)4*C_*C_;
    unsigned short* qh    = hbuf  + (size_t)NROWS*C_;
    unsigned short* kh    = qh    + (size_t)NROWS*C_;
    unsigned short* vh    = kh    + (size_t)NROWS*C_;
    unsigned short* cbuf  = qh;                        // fc chunk out (dense path)
    float* imp    = (float*)(vh + (size_t)NROWS*C_);
    int*   nsurv  = (int*)(imp + NROWS);
    float* abuf   = (float*)(nsurv + 8);
    float* rowbuf = abuf + 4*C_;
    float* linvbuf = rowbuf + C_;                      // 64*2048 fp32

    float* out_x    = (float*)d_out;
    float* out_mask = out_x + (size_t)NROWS*C_;
    float* out_loss = out_mask + NROWS;

    // prep: LN1 + qkv weight cvt + zero imp/nsurv
    hipLaunchKernelGGL(prep_kernel, dim3(NROWS), dim3(256), 0, stream,
                       x, ln1w, ln1b, hbuf, cattn_w, wqkv, imp, nsurv);
    // QK GEMM (N = 2048) -> qh/kh head-major (q pre-scaled by QSCALE)
    hipLaunchKernelGGL((gemm_bf16<3>), dim3(16, 64), dim3(256), 0, stream,
                       hbuf, wqkv, cattn_b, nullptr, nullptr, nullptr,
                       C_, C_, C_, 0, 0, nullptr, qh, kh, vh, nullptr, 16, 64);
    // attention: two barrier-free streaming passes
    hipLaunchKernelGGL(attn_rowsum, dim3(64*32), dim3(256), 0, stream,
                       qh, kh, amask, linvbuf);
    hipLaunchKernelGGL(attn_colsum, dim3(64*32), dim3(256), 0, stream,
                       qh, kh, amask, linvbuf, imp);
    hipLaunchKernelGGL(mask_finalize, dim3(NROWS/256), dim3(256), 0, stream,
                       imp, amask, prot, thr, out_mask, out_loss, nsurv);

    // ---- dense fallback path (persistent grids; early-exit when nsurv == 0) ----
    hipLaunchKernelGGL(cvt3_bf16, dim3(512), dim3(256), 0, stream,
                       cproj_w, fcw, fcpw, wproj, wfc, wfcp, nsurv);
    hipLaunchKernelGGL((gemm_bf16<3>), dim3(512), dim3(256), 0, stream,
                       hbuf, wqkv + (size_t)2048*C_, cattn_b + 2048, nullptr, nullptr, nullptr,
                       C_, C_, C_, 0, 2048, nullptr, qh, kh, vh, nsurv, 8, 64);
    hipLaunchKernelGGL(attn_full, dim3(512), dim3(256), 0, stream,
                       qh, kh, vh, amask, hbuf, nsurv);
    hipLaunchKernelGGL((gemm_bf16<4>), dim3(512), dim3(256), 0, stream,
                       hbuf, wproj, cproj_b, x, out_x, nullptr,
                       C_, C_, C_, C_, 0, out_mask, nullptr, nullptr, nullptr, nsurv, 8, 64);
    hipLaunchKernelGGL(ln_bf16, dim3(512), dim3(256), 0, stream,
                       out_x, ln2w, ln2b, hbuf, nsurv, NROWS);
    for (int j = 0; j < 2; j++) {
        hipLaunchKernelGGL((gemm_bf16<1>), dim3(512), dim3(256), 0, stream,
                           hbuf, wfc + (size_t)j*2048*C_, fcb + j*2048, nullptr, nullptr, cbuf,
                           C_, C_, C_, 2048, 0, nullptr, nullptr, nullptr, nullptr, nsurv, 16, 64);
        hipLaunchKernelGGL((gemm_bf16<2>), dim3(512), dim3(256), 0, stream,
                           cbuf, wfcp + (size_t)j*2048, (j == 0) ? fcpb : nullptr, out_x, out_x, nullptr,
                           2048, 2048, 4*C_, C_, 0, nullptr, nullptr, nullptr, nullptr, nsurv, 8, 64);
    }

    // ---- all-pruned fast path (early-exit when nsurv != 0) ----
    hipLaunchKernelGGL(ap_fc,    dim3(4*C_/4), dim3(256), 0, stream, nsurv, ln2b, fcw, fcb, abuf);
    hipLaunchKernelGGL(ap_fcp,   dim3(C_/4),   dim3(256), 0, stream, nsurv, abuf, fcpw, fcpb, rowbuf);
    hipLaunchKernelGGL(ap_bcast, dim3(512),    dim3(256), 0, stream, nsurv, rowbuf, out_x);
}